// Round 1
// baseline (4973.544 us; speedup 1.0000x reference)
//
#include <hip/hip_runtime.h>

#define DEVI __device__ __forceinline__

constexpr int N_  = 8192;
constexpr int K_  = 15;
constexpr int E_  = N_ * K_;     // 122880
constexpr int FTS = 12;
constexpr float DT_ = 0.25f;

DEVI float sigf(float x) { return 1.0f / (1.0f + __expf(-x)); }

// ---------------------------------------------------------------- zero accum
__global__ void k_zero(float* ss) {
  if (threadIdx.x < 13) ss[threadIdx.x] = 0.f;  // ss[0..11] = terr ssq per step, ss[12] = ccost
}

// ---------------------------------------------------------------- edge static (rad, size feats)
__global__ __launch_bounds__(256) void k_edge_static(
    const int* __restrict__ e1, const int* __restrict__ e2,
    const float* __restrict__ nsize, float* __restrict__ rad, float* __restrict__ szf)
{
  int e = blockIdx.x * 256 + threadIdx.x;
  if (e >= E_) return;
  int i1 = e1[e], i2 = e2[e];
  float s1x = nsize[i1*2+0], s1y = nsize[i1*2+1];
  float s2x = nsize[i2*2+0], s2y = nsize[i2*2+1];
  rad[e] = 0.5f * (sqrtf(s1x*s1x + s1y*s1y) + sqrtf(s2x*s2x + s2y*s2y));
  *(float4*)&szf[e*4] = make_float4(s1x, s1y, s2x, s2y);
}

// ---------------------------------------------------------------- xz GEMM: h0g + gi
// cols 0..255 -> gh0 (W_gh), cols 256..1023 -> gi (W_gru_ih). K=264.
__global__ __launch_bounds__(256) void k_xz_gemm(
    const float* __restrict__ hist, const float* __restrict__ z,
    const float* __restrict__ W_gh, const float* __restrict__ b_gh,
    const float* __restrict__ W_gih, const float* __restrict__ b_gih,
    float* __restrict__ gh0, float* __restrict__ gi)
{
  __shared__ __align__(16) float A[32][268];
  const int n0 = blockIdx.y * 32;
  const int c0 = blockIdx.x * 64;
  const int tid = threadIdx.x;
  for (int idx = tid; idx < 32 * 264; idx += 256) {
    int r = idx / 264, k = idx % 264;
    A[r][k] = (k < 256) ? hist[(size_t)(n0 + r) * 256 + k] : z[(n0 + r) * 8 + (k - 256)];
  }
  __syncthreads();
  const int cl = tid & 63, ng = tid >> 6;
  const int col = c0 + cl;
  const bool isGh = (col < 256);
  const float* W = isGh ? W_gh : W_gih;
  const int wcol = isGh ? col : col - 256;
  const int wld  = isGh ? 256 : 768;
  float acc[8];
#pragma unroll
  for (int i = 0; i < 8; i++) acc[i] = 0.f;
  for (int k = 0; k < 264; k += 4) {
    float b0 = W[(k+0)*wld + wcol];
    float b1 = W[(k+1)*wld + wcol];
    float b2 = W[(k+2)*wld + wcol];
    float b3 = W[(k+3)*wld + wcol];
#pragma unroll
    for (int i = 0; i < 8; i++) {
      const float4 a = *(const float4*)&A[ng*8 + i][k];
      acc[i] += a.x*b0 + a.y*b1 + a.z*b2 + a.w*b3;
    }
  }
  const float bias = isGh ? b_gh[wcol] : b_gih[wcol];
#pragma unroll
  for (int i = 0; i < 8; i++) {
    int n = n0 + ng*8 + i;
    float v = acc[i] + bias;
    if (isGh) gh0[(size_t)n*256 + wcol] = v;
    else      gi[(size_t)n*768 + wcol] = v;
  }
}

// ---------------------------------------------------------------- GRU step
__global__ __launch_bounds__(256) void k_gru(
    const float* __restrict__ h_in, const float* __restrict__ W_hh,
    const float* __restrict__ b_hh, const float* __restrict__ gi,
    float* __restrict__ h_out)
{
  __shared__ __align__(16) float A[32][260];
  const int n0 = blockIdx.y * 32;
  const int j0 = blockIdx.x * 64;
  const int tid = threadIdx.x;
  for (int idx = tid; idx < 32 * 256; idx += 256) {
    int r = idx >> 8, k = idx & 255;
    A[r][k] = h_in[(size_t)(n0 + r) * 256 + k];
  }
  __syncthreads();
  const int jl = tid & 63, ng = tid >> 6;
  const int j = j0 + jl;
  float ar[8], az[8], an[8];
#pragma unroll
  for (int i = 0; i < 8; i++) { ar[i] = 0.f; az[i] = 0.f; an[i] = 0.f; }
  for (int k = 0; k < 256; k += 4) {
    float br[4], bz[4], bn[4];
#pragma unroll
    for (int q = 0; q < 4; q++) {
      br[q] = W_hh[(k+q)*768 + j];
      bz[q] = W_hh[(k+q)*768 + 256 + j];
      bn[q] = W_hh[(k+q)*768 + 512 + j];
    }
#pragma unroll
    for (int i = 0; i < 8; i++) {
      const float4 a = *(const float4*)&A[ng*8 + i][k];
      ar[i] += a.x*br[0] + a.y*br[1] + a.z*br[2] + a.w*br[3];
      az[i] += a.x*bz[0] + a.y*bz[1] + a.z*bz[2] + a.w*bz[3];
      an[i] += a.x*bn[0] + a.y*bn[1] + a.z*bn[2] + a.w*bn[3];
    }
  }
  const float bbr = b_hh[j], bbz = b_hh[256 + j], bbn = b_hh[512 + j];
#pragma unroll
  for (int i = 0; i < 8; i++) {
    int n = n0 + ng*8 + i;
    float ir  = gi[(size_t)n*768 + j];
    float iz  = gi[(size_t)n*768 + 256 + j];
    float inn = gi[(size_t)n*768 + 512 + j];
    float r = sigf(ir + ar[i] + bbr);
    float u = sigf(iz + az[i] + bbz);
    float hold = A[ng*8 + i][j];
    float nh = (1.f - u) * tanhf(inn + r * (an[i] + bbn)) + u * hold;
    h_out[(size_t)n*256 + j] = nh;
  }
}

// ---------------------------------------------------------------- des projection (per wave: 1 node)
__global__ __launch_bounds__(256) void k_proj(
    const float* __restrict__ h, const float* __restrict__ W,
    const float* __restrict__ b, float* __restrict__ des_t)
{
  const int lane = threadIdx.x & 63;
  const int wv = threadIdx.x >> 6;
  const int n = blockIdx.x * 4 + wv;
  float p0 = 0.f, p1 = 0.f;
  for (int i = lane; i < 256; i += 64) {
    float hv = h[(size_t)n*256 + i];
    p0 += hv * W[i*2];
    p1 += hv * W[i*2 + 1];
  }
#pragma unroll
  for (int off = 32; off; off >>= 1) {
    p0 += __shfl_down(p0, off);
    p1 += __shfl_down(p1, off);
  }
  if (lane == 0) { des_t[n*2] = p0 + b[0]; des_t[n*2 + 1] = p1 + b[1]; }
}

// ---------------------------------------------------------------- LSTM h0/c0 + prev copies
__global__ __launch_bounds__(256) void k_init_hc(
    const float* __restrict__ x_last, const float* __restrict__ x_st_last,
    const float* __restrict__ W_h0, const float* __restrict__ b_h0,
    const float* __restrict__ W_c0, const float* __restrict__ b_c0,
    float* __restrict__ h, float* __restrict__ c,
    float* __restrict__ prev, float* __restrict__ prev_st)
{
  const int n = blockIdx.x;
  const int j = threadIdx.x;
  float x0 = x_st_last[n*4], x1 = x_st_last[n*4+1], x2 = x_st_last[n*4+2], x3 = x_st_last[n*4+3];
  h[(size_t)n*256 + j] = b_h0[j] + x0*W_h0[j] + x1*W_h0[256+j] + x2*W_h0[512+j] + x3*W_h0[768+j];
  c[(size_t)n*256 + j] = b_c0[j] + x0*W_c0[j] + x1*W_c0[256+j] + x2*W_c0[512+j] + x3*W_c0[768+j];
  if (j < 4) prev[n*4 + j] = x_last[n*4 + j];
  else if (j < 8) prev_st[n*4 + (j-4)] = x_st_last[n*4 + (j-4)];
}

// ---------------------------------------------------------------- collision cost
__global__ __launch_bounds__(256) void k_ccost(
    const float* __restrict__ prev, const int* __restrict__ e1, const int* __restrict__ e2,
    const float* __restrict__ rad, float* __restrict__ cc)
{
  int e = blockIdx.x * 256 + threadIdx.x;
  float v = 0.f;
  if (e < E_) {
    int i1 = e1[e], i2 = e2[e];
    float dx = prev[i1*4]   - prev[i2*4];
    float dy = prev[i1*4+1] - prev[i2*4+1];
    float d = sqrtf(dx*dx + dy*dy);
    v = fmaxf(rad[e] - d, 0.f);
  }
#pragma unroll
  for (int off = 32; off; off >>= 1) v += __shfl_down(v, off);
  __shared__ float red[4];
  int lane = threadIdx.x & 63, wv = threadIdx.x >> 6;
  if (lane == 0) red[wv] = v;
  __syncthreads();
  if (threadIdx.x == 0) atomicAdd(cc, red[0] + red[1] + red[2] + red[3]);
}

// ---------------------------------------------------------------- rel / next_wp / terr ssq
__global__ __launch_bounds__(256) void k_rel(
    const float* __restrict__ prev_st, const float* __restrict__ x_st_last,
    const float* __restrict__ des_p, const float* __restrict__ des_t,
    const float* __restrict__ des_n,
    float* __restrict__ rel, float* __restrict__ nwp, float* __restrict__ nwp2,
    float* __restrict__ ss_t)
{
  const int n = blockIdx.x * 256 + threadIdx.x;
  float4 ps = *(const float4*)&prev_st[n*4];
  float r0, r1, r2, r3;
  if (des_p) {
    float4 xs = *(const float4*)&x_st_last[n*4];
    r0 = ps.x - xs.x - des_p[n*2];
    r1 = ps.y - xs.y - des_p[n*2 + 1];
    r2 = ps.z - xs.z;
    r3 = ps.w - xs.w;
  } else { r0 = ps.x; r1 = ps.y; r2 = ps.z; r3 = ps.w; }
  *(float4*)&rel[n*4] = make_float4(r0, r1, r2, r3);
  nwp[n*2]     = des_t[n*2]     - ps.x;
  nwp[n*2 + 1] = des_t[n*2 + 1] - ps.y;
  nwp2[n*2]     = des_n[n*2]     - ps.x;
  nwp2[n*2 + 1] = des_n[n*2 + 1] - ps.y;
  float v = r0*r0 + r1*r1;
#pragma unroll
  for (int off = 32; off; off >>= 1) v += __shfl_down(v, off);
  __shared__ float red[4];
  int lane = threadIdx.x & 63, wv = threadIdx.x >> 6;
  if (lane == 0) red[wv] = v;
  __syncthreads();
  if (threadIdx.x == 0) atomicAdd(ss_t, red[0] + red[1] + red[2] + red[3]);
}

// ---------------------------------------------------------------- fused edge-MLP + attention + ctx
// 2 nodes per block, 256 threads. Never materializes enc globally.
__global__ __launch_bounds__(256) void k_edge_attn(
    const float* __restrict__ prev, const float* __restrict__ szf,
    const int* __restrict__ nobs, const int* __restrict__ e1, const int* __restrict__ e2,
    const float* __restrict__ W_e1, const float* __restrict__ b_e1,
    const float* __restrict__ W_e2, const float* __restrict__ b_e2,
    const float* __restrict__ rel,
    const float* __restrict__ W_att1, const float* __restrict__ W_att2,
    const float* __restrict__ v_att,
    float* __restrict__ ctx)
{
  // smem layout (floats):
  //   [0,10240)     hidT[2][256][20]   (transposed hidden; ALIASED by enc[2][15][128] = 3840 after use)
  //   [10240,10480) feats[2][15][8]
  //   [10480,10512) flags[2][16]
  //   [10512,10544) relw[2][16]
  //   [10544,11024) sct[2][15][16]
  //   [11024,11056) attw[2][16]
  __shared__ __align__(16) float smem[11072];
  float* hidT  = smem;
  float* enc   = smem;
  float* feats = smem + 10240;
  float* flags = smem + 10480;
  float* relw  = smem + 10512;
  float* sct   = smem + 10544;
  float* attw  = smem + 11024;

  const int n0 = blockIdx.x * 2;
  const int tid = threadIdx.x;

  // ---- P0: features + flags + rel@W_att2
  if (tid < 30) {
    int nn = tid / 15, k = tid % 15;
    int idx = nobs[(n0 + nn) * 15 + k];
    float f[8] = {0,0,0,0,0,0,0,0};
    float fl = 0.f;
    if (idx > 0) {
      int e = idx - 1;
      int i1 = e1[e], i2 = e2[e];
#pragma unroll
      for (int d = 0; d < 4; d++) f[d] = prev[i2*4 + d] - prev[i1*4 + d];
#pragma unroll
      for (int d = 0; d < 4; d++) f[4 + d] = szf[(size_t)e*4 + d];
      fl = 1.f;
    }
#pragma unroll
    for (int d = 0; d < 8; d++) feats[(nn*15 + k)*8 + d] = f[d];
    flags[nn*16 + k] = fl;
  }
  if (tid >= 64 && tid < 96) {
    int t2 = tid - 64;
    int nn = t2 >> 4, a = t2 & 15;
    float s = 0.f;
#pragma unroll
    for (int d = 0; d < 4; d++) s += rel[(n0 + nn)*4 + d] * W_att2[d*16 + a];
    relw[nn*16 + a] = s;
  }
  __syncthreads();

  // ---- P1: hidden = relu(feat @ W_e1 + b_e1), stored TRANSPOSED hidT[nn][kk=tid][k]
  {
    float w[8];
#pragma unroll
    for (int d = 0; d < 8; d++) w[d] = W_e1[d*256 + tid];
    float be = b_e1[tid];
#pragma unroll
    for (int nn = 0; nn < 2; nn++) {
#pragma unroll
      for (int k = 0; k < 15; k++) {
        float hv = be;
#pragma unroll
        for (int d = 0; d < 8; d++) hv += feats[(nn*15 + k)*8 + d] * w[d];
        hidT[nn*5120 + tid*20 + k] = fmaxf(hv, 0.f);
      }
      hidT[nn*5120 + tid*20 + 15] = 0.f;  // pad (read by 4th float4)
    }
  }
  __syncthreads();

  // ---- P2: enc = hidden @ W_e2. thread = (cg 0..31, nn 0..1, q 0..3); tile 15k x 4c; K split by q.
  const int cg = tid & 31;
  const int nn = (tid >> 5) & 1;
  const int q  = tid >> 6;
  float acc[15][4];
#pragma unroll
  for (int k = 0; k < 15; k++) { acc[k][0]=0.f; acc[k][1]=0.f; acc[k][2]=0.f; acc[k][3]=0.f; }
  {
    const float4* Wp = (const float4*)W_e2;  // [kk][cg] float4
    const float* hrow = hidT + nn * 5120;
    for (int kk = q*64; kk < q*64 + 64; kk++) {
      float4 w = Wp[kk*32 + cg];
      const float4* hp = (const float4*)(hrow + kk*20);
      float4 h0v = hp[0], h1v = hp[1], h2v = hp[2], h3v = hp[3];
      float hk[16] = {h0v.x,h0v.y,h0v.z,h0v.w, h1v.x,h1v.y,h1v.z,h1v.w,
                      h2v.x,h2v.y,h2v.z,h2v.w, h3v.x,h3v.y,h3v.z,h3v.w};
#pragma unroll
      for (int k = 0; k < 15; k++) {
        acc[k][0] += hk[k]*w.x;
        acc[k][1] += hk[k]*w.y;
        acc[k][2] += hk[k]*w.z;
        acc[k][3] += hk[k]*w.w;
      }
    }
  }
  __syncthreads();  // all hidT reads done before enc alias-writes
  // reduce the 4 q-partials into enc (aliases hidT region)
#pragma unroll
  for (int p = 0; p < 4; p++) {
    if (q == p) {
#pragma unroll
      for (int k = 0; k < 15; k++) {
        float4 v = make_float4(acc[k][0], acc[k][1], acc[k][2], acc[k][3]);
        float4* ep = (float4*)&enc[nn*1920 + k*128 + cg*4];
        if (p == 0) {
          *ep = v;
        } else if (p < 3) {
          float4 o = *ep;
          o.x += v.x; o.y += v.y; o.z += v.z; o.w += v.w;
          *ep = o;
        } else {
          float4 o = *ep;
          float4 bb = *(const float4*)&b_e2[cg*4];
          float fl = flags[nn*16 + k];
          o.x = (o.x + v.x + bb.x) * fl;
          o.y = (o.y + v.y + bb.y) * fl;
          o.z = (o.z + v.z + bb.z) * fl;
          o.w = (o.w + v.w + bb.w) * fl;
          *ep = o;
        }
      }
    }
    __syncthreads();
  }

  // ---- P3: attention scores: sct[nn][k][a] = tanh(enc[k]·W_att1[:,a] + relw[a]) * v_att[a]
  for (int base = 0; base < 480; base += 256) {
    int id = base + tid;
    if (id < 480) {
      int ni = id / 240;
      int rm = id % 240;
      int k = rm >> 4;
      int a = rm & 15;
      const float4* er4 = (const float4*)&enc[ni*1920 + k*128];
      float s = 0.f;
#pragma unroll 8
      for (int c4 = 0; c4 < 32; c4++) {
        float4 ev = er4[c4];
        int cb = c4 * 4;
        s += ev.x * W_att1[(cb+0)*16 + a];
        s += ev.y * W_att1[(cb+1)*16 + a];
        s += ev.z * W_att1[(cb+2)*16 + a];
        s += ev.w * W_att1[(cb+3)*16 + a];
      }
      sct[(ni*15 + k)*16 + a] = tanhf(s + relw[ni*16 + a]) * v_att[a];
    }
  }
  __syncthreads();
  // softmax over k (serial per node; 2 threads)
  if (tid < 2) {
    int ni = tid;
    float sc[15], mx = -1e30f;
#pragma unroll
    for (int k = 0; k < 15; k++) {
      float s = 0.f;
#pragma unroll
      for (int a = 0; a < 16; a++) s += sct[(ni*15 + k)*16 + a];
      sc[k] = s; mx = fmaxf(mx, s);
    }
    float sum = 0.f;
#pragma unroll
    for (int k = 0; k < 15; k++) { sc[k] = __expf(sc[k] - mx); sum += sc[k]; }
    float inv = 1.f / sum;
#pragma unroll
    for (int k = 0; k < 15; k++) attw[ni*16 + k] = sc[k] * inv;
  }
  __syncthreads();
  // ---- P4: ctx = sum_k att[k] * enc[k]
  {
    const int c = tid & 127;
    const int ni = tid >> 7;
    float v = 0.f;
#pragma unroll
    for (int k = 0; k < 15; k++) v += attw[ni*16 + k] * enc[ni*1920 + k*128 + c];
    ctx[(size_t)(n0 + ni)*128 + c] = v;
  }
}

// ---------------------------------------------------------------- fused LSTM cell
// block = 32 nodes x 64 j; thread = (jl, ng) -> 8 nodes x 4 gates
__global__ __launch_bounds__(256) void k_lstm(
    const float* __restrict__ ctxg, const float* __restrict__ h_in,
    const float* __restrict__ W_ih, const float* __restrict__ W_hh,
    const float* __restrict__ b_ih, const float* __restrict__ b_hh,
    float* __restrict__ c_st, float* __restrict__ h_out)
{
  __shared__ __align__(16) float A[32][132];
  const int n0 = blockIdx.y * 32;
  const int j0 = blockIdx.x * 64;
  const int tid = threadIdx.x;
  const int jl = tid & 63, ng = tid >> 6;
  const int j = j0 + jl;
  float acc[8][4];
#pragma unroll
  for (int i = 0; i < 8; i++)
#pragma unroll
    for (int g = 0; g < 4; g++) acc[i][g] = 0.f;

  for (int ch = 0; ch < 3; ch++) {
    __syncthreads();
    for (int idx = tid; idx < 32 * 128; idx += 256) {
      int r = idx >> 7, kk = idx & 127;
      A[r][kk] = (ch == 0) ? ctxg[(size_t)(n0 + r)*128 + kk]
                           : h_in[(size_t)(n0 + r)*256 + (ch - 1)*128 + kk];
    }
    __syncthreads();
    const float* W = (ch == 0) ? W_ih : W_hh;
    const int kro = (ch == 0) ? 0 : (ch - 1) * 128;
    for (int kk = 0; kk < 128; kk += 4) {
      float b[4][4];
#pragma unroll
      for (int qq = 0; qq < 4; qq++)
#pragma unroll
        for (int g = 0; g < 4; g++)
          b[qq][g] = W[(size_t)(kro + kk + qq)*1024 + g*256 + j];
#pragma unroll
      for (int i = 0; i < 8; i++) {
        const float4 a = *(const float4*)&A[ng*8 + i][kk];
#pragma unroll
        for (int g = 0; g < 4; g++)
          acc[i][g] += a.x*b[0][g] + a.y*b[1][g] + a.z*b[2][g] + a.w*b[3][g];
      }
    }
  }
  const float bi = b_ih[j]       + b_hh[j];
  const float bf = b_ih[256 + j] + b_hh[256 + j];
  const float bg = b_ih[512 + j] + b_hh[512 + j];
  const float bo = b_ih[768 + j] + b_hh[768 + j];
#pragma unroll
  for (int i = 0; i < 8; i++) {
    int n = n0 + ng*8 + i;
    float g_i = sigf(acc[i][0] + bi);
    float g_f = sigf(acc[i][1] + bf);
    float g_g = tanhf(acc[i][2] + bg);
    float g_o = sigf(acc[i][3] + bo);
    float cv = g_f * c_st[(size_t)n*256 + j] + g_i * g_g;
    c_st[(size_t)n*256 + j] = cv;
    h_out[(size_t)n*256 + j] = g_o * tanhf(cv);
  }
}

// ---------------------------------------------------------------- action MLP + dynamics + outputs
__global__ __launch_bounds__(256) void k_action(
    const float* __restrict__ h, const float* __restrict__ z,
    const float* __restrict__ rel, const float* __restrict__ nwp, const float* __restrict__ nwp2,
    const float* __restrict__ W_a1, const float* __restrict__ b_a1,
    const float* __restrict__ W_a2, const float* __restrict__ b_a2,
    float* __restrict__ prev, float* __restrict__ prev_st,
    float* __restrict__ outS, float* __restrict__ outU)
{
  __shared__ __align__(16) float A[16][276];
  __shared__ __align__(16) float H[16][260];
  __shared__ float U[16][2];
  const int n0 = blockIdx.x * 16;
  const int tid = threadIdx.x;
  for (int idx = tid; idx < 16 * 272; idx += 256) {
    int r = idx / 272, k = idx % 272;
    int n = n0 + r;
    float v;
    if (k < 256)      v = h[(size_t)n*256 + k];
    else if (k < 264) v = z[n*8 + (k - 256)];
    else if (k < 268) v = rel[n*4 + (k - 264)];
    else if (k < 270) v = nwp[n*2 + (k - 268)];
    else              v = nwp2[n*2 + (k - 270)];
    A[r][k] = v;
  }
  __syncthreads();
  float acc[16];
#pragma unroll
  for (int r = 0; r < 16; r++) acc[r] = 0.f;
  for (int k = 0; k < 272; k += 4) {
    float w0 = W_a1[(k+0)*256 + tid];
    float w1 = W_a1[(k+1)*256 + tid];
    float w2 = W_a1[(k+2)*256 + tid];
    float w3 = W_a1[(k+3)*256 + tid];
#pragma unroll
    for (int r = 0; r < 16; r++) {
      const float4 a = *(const float4*)&A[r][k];
      acc[r] += a.x*w0 + a.y*w1 + a.z*w2 + a.w*w3;
    }
  }
  const float ba = b_a1[tid];
#pragma unroll
  for (int r = 0; r < 16; r++) H[r][tid] = fmaxf(acc[r] + ba, 0.f);
  __syncthreads();
  const int lane = tid & 63, wv = tid >> 6;
  for (int d = 0; d < 8; d++) {
    int r = wv*4 + (d >> 1);
    int cc = d & 1;
    float p = 0.f;
    for (int i = lane; i < 256; i += 64) p += H[r][i] * W_a2[i*2 + cc];
#pragma unroll
    for (int off = 32; off; off >>= 1) p += __shfl_down(p, off);
    if (lane == 0) U[r][cc] = tanhf(p + b_a2[cc]);
  }
  __syncthreads();
  if (tid < 16) {
    int n = n0 + tid;
    float ux = U[tid][0], uy = U[tid][1];
    float4 pv = *(const float4*)&prev[n*4];
    float4 ps = *(const float4*)&prev_st[n*4];
    const float hd = 0.5f * DT_ * DT_;
    float4 npv, nps;
    npv.x = pv.x + pv.z*DT_ + ux*hd;
    npv.y = pv.y + pv.w*DT_ + uy*hd;
    npv.z = pv.z + ux*DT_;
    npv.w = pv.w + uy*DT_;
    nps.x = ps.x + ps.z*DT_ + ux*hd;
    nps.y = ps.y + ps.w*DT_ + uy*hd;
    nps.z = ps.z + ux*DT_;
    nps.w = ps.w + uy*DT_;
    *(float4*)&prev[n*4] = npv;
    *(float4*)&prev_st[n*4] = nps;
    *(float4*)&outS[(size_t)n*4] = npv;
    outU[n*2]     = ux;
    outU[n*2 + 1] = uy;
  }
}

// ---------------------------------------------------------------- finalize scalars
__global__ void k_final(const float* __restrict__ ss, float* __restrict__ out) {
  if (threadIdx.x == 0) {
    float t = 0.f;
    for (int i = 0; i < FTS; i++) t += sqrtf(ss[i]);
    out[(size_t)FTS * N_ * 6]     = t / (float)N_;
    out[(size_t)FTS * N_ * 6 + 1] = ss[FTS];
  }
}

// ================================================================ launch
extern "C" void kernel_launch(void* const* d_in, const int* in_sizes, int n_in,
                              void* d_out, int out_size, void* d_ws, size_t ws_size,
                              hipStream_t stream) {
  (void)in_sizes; (void)n_in; (void)out_size; (void)ws_size;
  const float* x_last    = (const float*)d_in[0];
  const float* x_st_last = (const float*)d_in[1];
  const float* hist_enc  = (const float*)d_in[2];
  const float* z         = (const float*)d_in[3];
  const float* node_size = (const float*)d_in[4];
  const float* W_h0 = (const float*)d_in[5];
  const float* b_h0 = (const float*)d_in[6];
  const float* W_c0 = (const float*)d_in[7];
  const float* b_c0 = (const float*)d_in[8];
  const float* W_gh = (const float*)d_in[9];
  const float* b_gh = (const float*)d_in[10];
  const float* W_gih = (const float*)d_in[11];
  const float* W_ghh = (const float*)d_in[12];
  const float* b_gih = (const float*)d_in[13];
  const float* b_ghh = (const float*)d_in[14];
  const float* W_proj = (const float*)d_in[15];
  const float* b_proj = (const float*)d_in[16];
  const float* W_att1 = (const float*)d_in[17];
  const float* W_att2 = (const float*)d_in[18];
  const float* v_att  = (const float*)d_in[19];
  const float* W_lih = (const float*)d_in[20];
  const float* W_lhh = (const float*)d_in[21];
  const float* b_lih = (const float*)d_in[22];
  const float* b_lhh = (const float*)d_in[23];
  const float* W_e1 = (const float*)d_in[24];
  const float* b_e1 = (const float*)d_in[25];
  const float* W_e2 = (const float*)d_in[26];
  const float* b_e2 = (const float*)d_in[27];
  const float* W_a1 = (const float*)d_in[28];
  const float* b_a1 = (const float*)d_in[29];
  const float* W_a2 = (const float*)d_in[30];
  const float* b_a2 = (const float*)d_in[31];
  const int* e1   = (const int*)d_in[32];
  const int* e2   = (const int*)d_in[33];
  const int* nobs = (const int*)d_in[34];
  float* out = (float*)d_out;

  // workspace carve (floats)
  float* wsf     = (float*)d_ws;
  float* prev    = wsf;                     // 32768
  float* prev_st = wsf + 32768;             // 32768
  float* des     = wsf + 65536;             // 196608
  float* ss      = wsf + 262144;            // 16
  float* rad     = wsf + 262160;            // 122880
  float* szf     = wsf + 385040;            // 491520 -> ends 876560
  float* baseA   = wsf + 876560;            // union region: 10485760 floats
  // GRU phase view
  float* gh0 = baseA;
  float* gh1 = baseA + (size_t)N_ * 256;
  float* gi  = baseA + (size_t)2 * N_ * 256;
  // main phase view (aliases GRU-phase buffers, which are dead by then)
  float* hA   = baseA;
  float* hB   = baseA + (size_t)N_ * 256;
  float* cbuf = baseA + (size_t)2 * N_ * 256;
  float* ctx  = baseA + (size_t)3 * N_ * 256;
  float* rel  = baseA + (size_t)4 * N_ * 256;
  float* nwp  = rel + (size_t)N_ * 4;
  float* nwp2 = nwp + (size_t)N_ * 2;

  k_zero<<<1, 64, 0, stream>>>(ss);
  k_edge_static<<<(E_ + 255) / 256, 256, 0, stream>>>(e1, e2, node_size, rad, szf);

  // guide GRU phase
  k_xz_gemm<<<dim3(16, 256), 256, 0, stream>>>(hist_enc, z, W_gh, b_gh, W_gih, b_gih, gh0, gi);
  float* gcur = gh0;
  float* gnxt = gh1;
  for (int t = 0; t < FTS; t++) {
    k_gru<<<dim3(4, 256), 256, 0, stream>>>(gcur, W_ghh, b_ghh, gi, gnxt);
    k_proj<<<N_ / 4, 256, 0, stream>>>(gnxt, W_proj, b_proj, des + (size_t)t * N_ * 2);
    float* tmp = gcur; gcur = gnxt; gnxt = tmp;
  }

  // main rollout
  k_init_hc<<<N_, 256, 0, stream>>>(x_last, x_st_last, W_h0, b_h0, W_c0, b_c0,
                                    hA, cbuf, prev, prev_st);
  float* hcur = hA;
  float* hnxt = hB;
  for (int t = 0; t < FTS; t++) {
    const float* des_t = des + (size_t)t * N_ * 2;
    const float* des_n = des + (size_t)((t + 1 < FTS) ? t + 1 : FTS - 1) * N_ * 2;
    const float* des_p = (t > 0) ? des + (size_t)(t - 1) * N_ * 2 : nullptr;
    k_ccost<<<(E_ + 255) / 256, 256, 0, stream>>>(prev, e1, e2, rad, ss + 12);
    k_rel<<<N_ / 256, 256, 0, stream>>>(prev_st, x_st_last, des_p, des_t, des_n,
                                        rel, nwp, nwp2, ss + t);
    k_edge_attn<<<N_ / 2, 256, 0, stream>>>(prev, szf, nobs, e1, e2,
                                            W_e1, b_e1, W_e2, b_e2, rel,
                                            W_att1, W_att2, v_att, ctx);
    k_lstm<<<dim3(4, 256), 256, 0, stream>>>(ctx, hcur, W_lih, W_lhh, b_lih, b_lhh,
                                             cbuf, hnxt);
    k_action<<<N_ / 16, 256, 0, stream>>>(hnxt, z, rel, nwp, nwp2,
                                          W_a1, b_a1, W_a2, b_a2,
                                          prev, prev_st,
                                          out + (size_t)t * N_ * 4,
                                          out + (size_t)FTS * N_ * 4 + (size_t)t * N_ * 2);
    float* tmp = hcur; hcur = hnxt; hnxt = tmp;
  }
  k_final<<<1, 64, 0, stream>>>(ss, out);
}

// Round 2
// 4570.891 us; speedup vs baseline: 1.0881x; 1.0881x over previous
//
#include <hip/hip_runtime.h>

#define DEVI __device__ __forceinline__

constexpr int N_  = 8192;
constexpr int K_  = 15;
constexpr int E_  = N_ * K_;     // 122880
constexpr int FTS = 12;
constexpr float DT_ = 0.25f;

typedef __attribute__((ext_vector_type(8))) short short8x;
typedef __attribute__((ext_vector_type(4))) float float4x;

union U8 { unsigned int u[4]; short8x v; };

DEVI float sigf(float x) { return 1.0f / (1.0f + __expf(-x)); }
DEVI unsigned int f2u(float x) { union { float f; unsigned int u; } c; c.f = x; return c.u; }
DEVI float u2f(unsigned int x) { union { unsigned int u; float f; } c; c.u = x; return c.f; }

// ---------------------------------------------------------------- zero accum
__global__ void k_zero(float* ss) {
  if (threadIdx.x < 13) ss[threadIdx.x] = 0.f;  // ss[0..11] = terr ssq per step, ss[12] = ccost
}

// ---------------------------------------------------------------- edge static (rad, size feats)
__global__ __launch_bounds__(256) void k_edge_static(
    const int* __restrict__ e1, const int* __restrict__ e2,
    const float* __restrict__ nsize, float* __restrict__ rad, float* __restrict__ szf)
{
  int e = blockIdx.x * 256 + threadIdx.x;
  if (e >= E_) return;
  int i1 = e1[e], i2 = e2[e];
  float s1x = nsize[i1*2+0], s1y = nsize[i1*2+1];
  float s2x = nsize[i2*2+0], s2y = nsize[i2*2+1];
  rad[e] = 0.5f * (sqrtf(s1x*s1x + s1y*s1y) + sqrtf(s2x*s2x + s2y*s2y));
  *(float4*)&szf[e*4] = make_float4(s1x, s1y, s2x, s2y);
}

// ---------------------------------------------------------------- prep W_e2 into split-bf16 B-fragment layout
// frag fid = ks*8+nt covers B[k=32ks..+31][n=16nt..+15]; lane L holds B[32ks+(L>>4)*8+j][16nt+(L&15)].
// storage: ushort wsB[ (fid*2+hilo)*512 + L*8 + j ]
__global__ __launch_bounds__(256) void k_prep_B(
    const float* __restrict__ W_e2, unsigned short* __restrict__ wsB)
{
  int t = blockIdx.x * 256 + threadIdx.x;   // 0..8191
  int fid = t >> 6, L = t & 63;
  int ks = fid >> 3, nt = fid & 7;
  int k0 = ks * 32 + (L >> 4) * 8;
  int n  = nt * 16 + (L & 15);
  unsigned int hi[4], lo[4];
#pragma unroll
  for (int p = 0; p < 4; p++) {
    float w0 = W_e2[(size_t)(k0 + 2*p) * 128 + n];
    float w1 = W_e2[(size_t)(k0 + 2*p + 1) * 128 + n];
    unsigned int u0 = f2u(w0), u1 = f2u(w1);
    unsigned int h0 = u0 & 0xFFFF0000u, h1 = u1 & 0xFFFF0000u;
    hi[p] = (u0 >> 16) | h1;
    float l0 = w0 - u2f(h0), l1 = w1 - u2f(h1);
    lo[p] = (f2u(l0) >> 16) | (f2u(l1) & 0xFFFF0000u);
  }
  size_t base = (size_t)(fid * 2) * 512 + (size_t)L * 8;
  *(uint4*)(wsB + base)       = make_uint4(hi[0], hi[1], hi[2], hi[3]);
  *(uint4*)(wsB + base + 512) = make_uint4(lo[0], lo[1], lo[2], lo[3]);
}

// ---------------------------------------------------------------- xz GEMM: h0g + gi
__global__ __launch_bounds__(256) void k_xz_gemm(
    const float* __restrict__ hist, const float* __restrict__ z,
    const float* __restrict__ W_gh, const float* __restrict__ b_gh,
    const float* __restrict__ W_gih, const float* __restrict__ b_gih,
    float* __restrict__ gh0, float* __restrict__ gi)
{
  __shared__ __align__(16) float A[32][268];
  const int n0 = blockIdx.y * 32;
  const int c0 = blockIdx.x * 64;
  const int tid = threadIdx.x;
  for (int idx = tid; idx < 32 * 264; idx += 256) {
    int r = idx / 264, k = idx % 264;
    A[r][k] = (k < 256) ? hist[(size_t)(n0 + r) * 256 + k] : z[(n0 + r) * 8 + (k - 256)];
  }
  __syncthreads();
  const int cl = tid & 63, ng = tid >> 6;
  const int col = c0 + cl;
  const bool isGh = (col < 256);
  const float* W = isGh ? W_gh : W_gih;
  const int wcol = isGh ? col : col - 256;
  const int wld  = isGh ? 256 : 768;
  float acc[8];
#pragma unroll
  for (int i = 0; i < 8; i++) acc[i] = 0.f;
  for (int k = 0; k < 264; k += 4) {
    float b0 = W[(k+0)*wld + wcol];
    float b1 = W[(k+1)*wld + wcol];
    float b2 = W[(k+2)*wld + wcol];
    float b3 = W[(k+3)*wld + wcol];
#pragma unroll
    for (int i = 0; i < 8; i++) {
      const float4 a = *(const float4*)&A[ng*8 + i][k];
      acc[i] += a.x*b0 + a.y*b1 + a.z*b2 + a.w*b3;
    }
  }
  const float bias = isGh ? b_gh[wcol] : b_gih[wcol];
#pragma unroll
  for (int i = 0; i < 8; i++) {
    int n = n0 + ng*8 + i;
    float v = acc[i] + bias;
    if (isGh) gh0[(size_t)n*256 + wcol] = v;
    else      gi[(size_t)n*768 + wcol] = v;
  }
}

// ---------------------------------------------------------------- GRU step
__global__ __launch_bounds__(256) void k_gru(
    const float* __restrict__ h_in, const float* __restrict__ W_hh,
    const float* __restrict__ b_hh, const float* __restrict__ gi,
    float* __restrict__ h_out)
{
  __shared__ __align__(16) float A[32][260];
  const int n0 = blockIdx.y * 32;
  const int j0 = blockIdx.x * 64;
  const int tid = threadIdx.x;
  for (int idx = tid; idx < 32 * 256; idx += 256) {
    int r = idx >> 8, k = idx & 255;
    A[r][k] = h_in[(size_t)(n0 + r) * 256 + k];
  }
  __syncthreads();
  const int jl = tid & 63, ng = tid >> 6;
  const int j = j0 + jl;
  float ar[8], az[8], an[8];
#pragma unroll
  for (int i = 0; i < 8; i++) { ar[i] = 0.f; az[i] = 0.f; an[i] = 0.f; }
  for (int k = 0; k < 256; k += 4) {
    float br[4], bz[4], bn[4];
#pragma unroll
    for (int q = 0; q < 4; q++) {
      br[q] = W_hh[(k+q)*768 + j];
      bz[q] = W_hh[(k+q)*768 + 256 + j];
      bn[q] = W_hh[(k+q)*768 + 512 + j];
    }
#pragma unroll
    for (int i = 0; i < 8; i++) {
      const float4 a = *(const float4*)&A[ng*8 + i][k];
      ar[i] += a.x*br[0] + a.y*br[1] + a.z*br[2] + a.w*br[3];
      az[i] += a.x*bz[0] + a.y*bz[1] + a.z*bz[2] + a.w*bz[3];
      an[i] += a.x*bn[0] + a.y*bn[1] + a.z*bn[2] + a.w*bn[3];
    }
  }
  const float bbr = b_hh[j], bbz = b_hh[256 + j], bbn = b_hh[512 + j];
#pragma unroll
  for (int i = 0; i < 8; i++) {
    int n = n0 + ng*8 + i;
    float ir  = gi[(size_t)n*768 + j];
    float iz  = gi[(size_t)n*768 + 256 + j];
    float inn = gi[(size_t)n*768 + 512 + j];
    float r = sigf(ir + ar[i] + bbr);
    float u = sigf(iz + az[i] + bbz);
    float hold = A[ng*8 + i][j];
    float nh = (1.f - u) * tanhf(inn + r * (an[i] + bbn)) + u * hold;
    h_out[(size_t)n*256 + j] = nh;
  }
}

// ---------------------------------------------------------------- des projection
__global__ __launch_bounds__(256) void k_proj(
    const float* __restrict__ h, const float* __restrict__ W,
    const float* __restrict__ b, float* __restrict__ des_t)
{
  const int lane = threadIdx.x & 63;
  const int wv = threadIdx.x >> 6;
  const int n = blockIdx.x * 4 + wv;
  float p0 = 0.f, p1 = 0.f;
  for (int i = lane; i < 256; i += 64) {
    float hv = h[(size_t)n*256 + i];
    p0 += hv * W[i*2];
    p1 += hv * W[i*2 + 1];
  }
#pragma unroll
  for (int off = 32; off; off >>= 1) {
    p0 += __shfl_down(p0, off);
    p1 += __shfl_down(p1, off);
  }
  if (lane == 0) { des_t[n*2] = p0 + b[0]; des_t[n*2 + 1] = p1 + b[1]; }
}

// ---------------------------------------------------------------- LSTM h0/c0 + prev copies
__global__ __launch_bounds__(256) void k_init_hc(
    const float* __restrict__ x_last, const float* __restrict__ x_st_last,
    const float* __restrict__ W_h0, const float* __restrict__ b_h0,
    const float* __restrict__ W_c0, const float* __restrict__ b_c0,
    float* __restrict__ h, float* __restrict__ c,
    float* __restrict__ prev, float* __restrict__ prev_st)
{
  const int n = blockIdx.x;
  const int j = threadIdx.x;
  float x0 = x_st_last[n*4], x1 = x_st_last[n*4+1], x2 = x_st_last[n*4+2], x3 = x_st_last[n*4+3];
  h[(size_t)n*256 + j] = b_h0[j] + x0*W_h0[j] + x1*W_h0[256+j] + x2*W_h0[512+j] + x3*W_h0[768+j];
  c[(size_t)n*256 + j] = b_c0[j] + x0*W_c0[j] + x1*W_c0[256+j] + x2*W_c0[512+j] + x3*W_c0[768+j];
  if (j < 4) prev[n*4 + j] = x_last[n*4 + j];
  else if (j < 8) prev_st[n*4 + (j-4)] = x_st_last[n*4 + (j-4)];
}

// ---------------------------------------------------------------- fused edge-MLP(MFMA) + attention + ctx + ccost/rel/terr
// 4 nodes per block (wave w = node w). 2048 blocks.
__global__ __launch_bounds__(256, 2) void k_edge_attn(
    const float* __restrict__ prev, const float* __restrict__ prev_st,
    const float* __restrict__ x_st_last,
    const float* __restrict__ szf, const float* __restrict__ rad,
    const int* __restrict__ nobs, const int* __restrict__ e1, const int* __restrict__ e2,
    const float* __restrict__ W_e1, const float* __restrict__ b_e1,
    const unsigned short* __restrict__ wsB, const float* __restrict__ b_e2,
    const float* __restrict__ W_att1, const float* __restrict__ W_att2,
    const float* __restrict__ v_att,
    const float* __restrict__ des_p, const float* __restrict__ des_t,
    const float* __restrict__ des_n,
    float* __restrict__ relg, float* __restrict__ nwp, float* __restrict__ nwp2,
    float* __restrict__ ctx, float* __restrict__ ss_t, float* __restrict__ cc)
{
  // LDS layout (floats):
  //  enc   [4][16][136] @ 0      (8704)
  //  feats [4][16][8]   @ 8704   (512)
  //  watt1 [128][16]    @ 9216   (2048)
  //  sct   [4][15][16]  @ 11264  (960)
  //  flags [4][16]      @ 12224  (64)
  //  relv  [4][4]       @ 12288  (16)
  //  sck   [4][16]      @ 12304  (64)
  //  attw  [4][16]      @ 12368  (64)
  //  watt2 [4][16]      @ 12432  (64)
  //  vatt  [16]         @ 12496  (16)
  //  red   [8]          @ 12512  (8)
  __shared__ __align__(16) float smem[12520];
  float* sm_enc   = smem;
  float* sm_feats = smem + 8704;
  float* sm_watt1 = smem + 9216;
  float* sm_sct   = smem + 11264;
  float* sm_flags = smem + 12224;
  float* sm_relv  = smem + 12288;
  float* sm_sck   = smem + 12304;
  float* sm_attw  = smem + 12368;
  float* sm_watt2 = smem + 12432;
  float* sm_vatt  = smem + 12496;
  float* sm_red   = smem + 12512;

  const int n0  = blockIdx.x * 4;
  const int tid = threadIdx.x;
  const int lane = tid & 63;
  const int g    = tid >> 6;        // wave id = node slot

  // ---- P0: feats/flags/ccost (wave 0), rel (threads 64..67), stage small weights
  for (int i = tid; i < 2048; i += 256) sm_watt1[i] = W_att1[i];
  if (tid >= 176 && tid < 192) sm_vatt[tid - 176] = v_att[tid - 176];
  if (tid >= 192) sm_watt2[tid - 192] = W_att2[tid - 192];

  if (tid < 64) {
    float v = 0.f;
    if (tid < 60) {
      int gg = tid / 15, k = tid % 15;
      int idx = nobs[(n0 + gg) * 15 + k];
      float f[8] = {0,0,0,0,0,0,0,0};
      float fl = 0.f;
      if (idx > 0) {
        int e = idx - 1;
        int i1 = e1[e], i2 = e2[e];
#pragma unroll
        for (int d = 0; d < 4; d++) f[d] = prev[i2*4 + d] - prev[i1*4 + d];
        float4 sz = *(const float4*)&szf[(size_t)e*4];
        f[4] = sz.x; f[5] = sz.y; f[6] = sz.z; f[7] = sz.w;
        fl = 1.f;
        float dist = sqrtf(f[0]*f[0] + f[1]*f[1]);
        v = fmaxf(rad[e] - dist, 0.f);
      }
#pragma unroll
      for (int d = 0; d < 8; d++) sm_feats[(gg*16 + k)*8 + d] = f[d];
      sm_flags[gg*16 + k] = fl;
    } else {
      int gg = tid - 60;
#pragma unroll
      for (int d = 0; d < 8; d++) sm_feats[(gg*16 + 15)*8 + d] = 0.f;
      sm_flags[gg*16 + 15] = 0.f;
    }
    // ccost wave-reduce (all 64 lanes participate)
#pragma unroll
    for (int off = 32; off; off >>= 1) v += __shfl_down(v, off);
    if (tid == 0) atomicAdd(cc, v);
  } else if (tid < 68) {
    int gg = tid - 64;
    int n = n0 + gg;
    float4 ps = *(const float4*)&prev_st[n*4];
    float r0, r1, r2, r3;
    if (des_p) {
      float4 xs = *(const float4*)&x_st_last[n*4];
      r0 = ps.x - xs.x - des_p[n*2];
      r1 = ps.y - xs.y - des_p[n*2 + 1];
      r2 = ps.z - xs.z;
      r3 = ps.w - xs.w;
    } else { r0 = ps.x; r1 = ps.y; r2 = ps.z; r3 = ps.w; }
    sm_relv[gg*4+0] = r0; sm_relv[gg*4+1] = r1; sm_relv[gg*4+2] = r2; sm_relv[gg*4+3] = r3;
    *(float4*)&relg[n*4] = make_float4(r0, r1, r2, r3);
    nwp[n*2]      = des_t[n*2]     - ps.x;
    nwp[n*2 + 1]  = des_t[n*2 + 1] - ps.y;
    nwp2[n*2]     = des_n[n*2]     - ps.x;
    nwp2[n*2 + 1] = des_n[n*2 + 1] - ps.y;
    sm_red[gg] = r0*r0 + r1*r1;
  }
  __syncthreads();
  if (tid == 64) atomicAdd(ss_t, sm_red[0] + sm_red[1] + sm_red[2] + sm_red[3]);

  // ---- P1: hidden = relu(feat@W_e1+b_e1) built directly in A-frag lane layout,
  //          split to bf16 hi/lo in registers. lane = (m = lane&15 row, q = lane>>4 k-quad)
  const int q = lane >> 4, m = lane & 15;
  float f[8];
  {
    const float4 fa = *(const float4*)&sm_feats[(g*16 + m)*8];
    const float4 fb = *(const float4*)&sm_feats[(g*16 + m)*8 + 4];
    f[0]=fa.x; f[1]=fa.y; f[2]=fa.z; f[3]=fa.w; f[4]=fb.x; f[5]=fb.y; f[6]=fb.z; f[7]=fb.w;
  }
  short8x aHi[8], aLo[8];
  const float4* We14 = (const float4*)W_e1;   // [d][256] -> float4 idx d*64 + k4
  const float4* Be14 = (const float4*)b_e1;
#pragma unroll
  for (int ks = 0; ks < 8; ks++) {
    float h[8];
    {
      float4 b0 = Be14[8*ks + 2*q];
      float4 b1 = Be14[8*ks + 2*q + 1];
      h[0]=b0.x; h[1]=b0.y; h[2]=b0.z; h[3]=b0.w; h[4]=b1.x; h[5]=b1.y; h[6]=b1.z; h[7]=b1.w;
    }
#pragma unroll
    for (int d = 0; d < 8; d++) {
      float4 wa = We14[d*64 + ks*8 + 2*q];
      float4 wb = We14[d*64 + ks*8 + 2*q + 1];
      h[0] += f[d]*wa.x; h[1] += f[d]*wa.y; h[2] += f[d]*wa.z; h[3] += f[d]*wa.w;
      h[4] += f[d]*wb.x; h[5] += f[d]*wb.y; h[6] += f[d]*wb.z; h[7] += f[d]*wb.w;
    }
    U8 ph, pl;
#pragma unroll
    for (int p = 0; p < 4; p++) {
      float a0 = fmaxf(h[2*p], 0.f), a1 = fmaxf(h[2*p+1], 0.f);
      unsigned int u0 = f2u(a0), u1 = f2u(a1);
      unsigned int h0 = u0 & 0xFFFF0000u, h1 = u1 & 0xFFFF0000u;
      ph.u[p] = (u0 >> 16) | h1;
      float l0 = a0 - u2f(h0), l1 = a1 - u2f(h1);
      pl.u[p] = (f2u(l0) >> 16) | (f2u(l1) & 0xFFFF0000u);
    }
    aHi[ks] = ph.v;
    aLo[ks] = pl.v;
  }

  // ---- P2: enc = hidden @ W_e2 via split-bf16 MFMA; epilogue to LDS enc
#pragma unroll
  for (int nt = 0; nt < 8; nt++) {
    float4x acc = {0.f, 0.f, 0.f, 0.f};
#pragma unroll
    for (int ks = 0; ks < 8; ks++) {
      size_t off = (size_t)((ks*8 + nt)*2) * 512 + (size_t)lane * 8;
      short8x bh = *(const short8x*)(wsB + off);
      short8x bl = *(const short8x*)(wsB + off + 512);
      acc = __builtin_amdgcn_mfma_f32_16x16x32_bf16(aHi[ks], bl, acc, 0, 0, 0);
      acc = __builtin_amdgcn_mfma_f32_16x16x32_bf16(aLo[ks], bh, acc, 0, 0, 0);
      acc = __builtin_amdgcn_mfma_f32_16x16x32_bf16(aHi[ks], bh, acc, 0, 0, 0);
    }
    int col = nt*16 + m;          // C-layout: col = lane&15
    float b2 = b_e2[col];
#pragma unroll
    for (int i = 0; i < 4; i++) {
      int r = q*4 + i;            // C-layout: row = (lane>>4)*4 + reg
      sm_enc[(g*16 + r)*136 + col] = (acc[i] + b2) * sm_flags[g*16 + r];
    }
  }
  __syncthreads();

  // ---- P3: sct[g][k][a] = tanh(enc[k]·W_att1[:,a] + rel·W_att2[:,a]) * v_att[a]
  for (int id = tid; id < 960; id += 256) {
    int gg = id / 240;
    int rm = id % 240;
    int k = rm >> 4;
    int a = rm & 15;
    float s = sm_relv[gg*4+0]*sm_watt2[a] + sm_relv[gg*4+1]*sm_watt2[16+a]
            + sm_relv[gg*4+2]*sm_watt2[32+a] + sm_relv[gg*4+3]*sm_watt2[48+a];
    const float4* er = (const float4*)&sm_enc[(gg*16 + k)*136];
#pragma unroll 8
    for (int c4 = 0; c4 < 32; c4++) {
      float4 e = er[c4];
      int cb = c4*4;
      s += e.x * sm_watt1[(cb+0)*16 + a];
      s += e.y * sm_watt1[(cb+1)*16 + a];
      s += e.z * sm_watt1[(cb+2)*16 + a];
      s += e.w * sm_watt1[(cb+3)*16 + a];
    }
    sm_sct[(gg*15 + k)*16 + a] = tanhf(s) * sm_vatt[a];
  }
  __syncthreads();
  // ---- P4: softmax over k
  if (tid < 60) {
    int gg = tid / 15, k = tid % 15;
    const float4* sp = (const float4*)&sm_sct[(gg*15 + k)*16];
    float4 s0 = sp[0], s1 = sp[1], s2 = sp[2], s3 = sp[3];
    sm_sck[gg*16 + k] = s0.x+s0.y+s0.z+s0.w + s1.x+s1.y+s1.z+s1.w
                      + s2.x+s2.y+s2.z+s2.w + s3.x+s3.y+s3.z+s3.w;
  }
  __syncthreads();
  if (tid < 4) {
    float sc[15], mx = -1e30f;
#pragma unroll
    for (int k = 0; k < 15; k++) { sc[k] = sm_sck[tid*16 + k]; mx = fmaxf(mx, sc[k]); }
    float sum = 0.f;
#pragma unroll
    for (int k = 0; k < 15; k++) { sc[k] = __expf(sc[k] - mx); sum += sc[k]; }
    float inv = 1.f / sum;
#pragma unroll
    for (int k = 0; k < 15; k++) sm_attw[tid*16 + k] = sc[k] * inv;
  }
  __syncthreads();
  // ---- P5: ctx = sum_k att[k] * enc[k]
#pragma unroll
  for (int rep = 0; rep < 2; rep++) {
    int gg = rep*2 + (tid >> 7);
    int c = tid & 127;
    float v = 0.f;
#pragma unroll
    for (int k = 0; k < 15; k++) v += sm_attw[gg*16 + k] * sm_enc[(gg*16 + k)*136 + c];
    ctx[(size_t)(n0 + gg)*128 + c] = v;
  }
}

// ---------------------------------------------------------------- fused LSTM cell
__global__ __launch_bounds__(256) void k_lstm(
    const float* __restrict__ ctxg, const float* __restrict__ h_in,
    const float* __restrict__ W_ih, const float* __restrict__ W_hh,
    const float* __restrict__ b_ih, const float* __restrict__ b_hh,
    float* __restrict__ c_st, float* __restrict__ h_out)
{
  __shared__ __align__(16) float A[32][132];
  const int n0 = blockIdx.y * 32;
  const int j0 = blockIdx.x * 64;
  const int tid = threadIdx.x;
  const int jl = tid & 63, ng = tid >> 6;
  const int j = j0 + jl;
  float acc[8][4];
#pragma unroll
  for (int i = 0; i < 8; i++)
#pragma unroll
    for (int gg = 0; gg < 4; gg++) acc[i][gg] = 0.f;

  for (int ch = 0; ch < 3; ch++) {
    __syncthreads();
    for (int idx = tid; idx < 32 * 128; idx += 256) {
      int r = idx >> 7, kk = idx & 127;
      A[r][kk] = (ch == 0) ? ctxg[(size_t)(n0 + r)*128 + kk]
                           : h_in[(size_t)(n0 + r)*256 + (ch - 1)*128 + kk];
    }
    __syncthreads();
    const float* W = (ch == 0) ? W_ih : W_hh;
    const int kro = (ch == 0) ? 0 : (ch - 1) * 128;
    for (int kk = 0; kk < 128; kk += 4) {
      float b[4][4];
#pragma unroll
      for (int qq = 0; qq < 4; qq++)
#pragma unroll
        for (int gg = 0; gg < 4; gg++)
          b[qq][gg] = W[(size_t)(kro + kk + qq)*1024 + gg*256 + j];
#pragma unroll
      for (int i = 0; i < 8; i++) {
        const float4 a = *(const float4*)&A[ng*8 + i][kk];
#pragma unroll
        for (int gg = 0; gg < 4; gg++)
          acc[i][gg] += a.x*b[0][gg] + a.y*b[1][gg] + a.z*b[2][gg] + a.w*b[3][gg];
      }
    }
  }
  const float bi = b_ih[j]       + b_hh[j];
  const float bf = b_ih[256 + j] + b_hh[256 + j];
  const float bg = b_ih[512 + j] + b_hh[512 + j];
  const float bo = b_ih[768 + j] + b_hh[768 + j];
#pragma unroll
  for (int i = 0; i < 8; i++) {
    int n = n0 + ng*8 + i;
    float g_i = sigf(acc[i][0] + bi);
    float g_f = sigf(acc[i][1] + bf);
    float g_g = tanhf(acc[i][2] + bg);
    float g_o = sigf(acc[i][3] + bo);
    float cv = g_f * c_st[(size_t)n*256 + j] + g_i * g_g;
    c_st[(size_t)n*256 + j] = cv;
    h_out[(size_t)n*256 + j] = g_o * tanhf(cv);
  }
}

// ---------------------------------------------------------------- action MLP + dynamics + outputs
__global__ __launch_bounds__(256) void k_action(
    const float* __restrict__ h, const float* __restrict__ z,
    const float* __restrict__ rel, const float* __restrict__ nwp, const float* __restrict__ nwp2,
    const float* __restrict__ W_a1, const float* __restrict__ b_a1,
    const float* __restrict__ W_a2, const float* __restrict__ b_a2,
    float* __restrict__ prev, float* __restrict__ prev_st,
    float* __restrict__ outS, float* __restrict__ outU)
{
  __shared__ __align__(16) float A[16][276];
  __shared__ __align__(16) float H[16][260];
  __shared__ float U[16][2];
  const int n0 = blockIdx.x * 16;
  const int tid = threadIdx.x;
  for (int idx = tid; idx < 16 * 272; idx += 256) {
    int r = idx / 272, k = idx % 272;
    int n = n0 + r;
    float v;
    if (k < 256)      v = h[(size_t)n*256 + k];
    else if (k < 264) v = z[n*8 + (k - 256)];
    else if (k < 268) v = rel[n*4 + (k - 264)];
    else if (k < 270) v = nwp[n*2 + (k - 268)];
    else              v = nwp2[n*2 + (k - 270)];
    A[r][k] = v;
  }
  __syncthreads();
  float acc[16];
#pragma unroll
  for (int r = 0; r < 16; r++) acc[r] = 0.f;
  for (int k = 0; k < 272; k += 4) {
    float w0 = W_a1[(k+0)*256 + tid];
    float w1 = W_a1[(k+1)*256 + tid];
    float w2 = W_a1[(k+2)*256 + tid];
    float w3 = W_a1[(k+3)*256 + tid];
#pragma unroll
    for (int r = 0; r < 16; r++) {
      const float4 a = *(const float4*)&A[r][k];
      acc[r] += a.x*w0 + a.y*w1 + a.z*w2 + a.w*w3;
    }
  }
  const float ba = b_a1[tid];
#pragma unroll
  for (int r = 0; r < 16; r++) H[r][tid] = fmaxf(acc[r] + ba, 0.f);
  __syncthreads();
  const int lane = tid & 63, wv = tid >> 6;
  for (int d = 0; d < 8; d++) {
    int r = wv*4 + (d >> 1);
    int cc = d & 1;
    float p = 0.f;
    for (int i = lane; i < 256; i += 64) p += H[r][i] * W_a2[i*2 + cc];
#pragma unroll
    for (int off = 32; off; off >>= 1) p += __shfl_down(p, off);
    if (lane == 0) U[r][cc] = tanhf(p + b_a2[cc]);
  }
  __syncthreads();
  if (tid < 16) {
    int n = n0 + tid;
    float ux = U[tid][0], uy = U[tid][1];
    float4 pv = *(const float4*)&prev[n*4];
    float4 ps = *(const float4*)&prev_st[n*4];
    const float hd = 0.5f * DT_ * DT_;
    float4 npv, nps;
    npv.x = pv.x + pv.z*DT_ + ux*hd;
    npv.y = pv.y + pv.w*DT_ + uy*hd;
    npv.z = pv.z + ux*DT_;
    npv.w = pv.w + uy*DT_;
    nps.x = ps.x + ps.z*DT_ + ux*hd;
    nps.y = ps.y + ps.w*DT_ + uy*hd;
    nps.z = ps.z + ux*DT_;
    nps.w = ps.w + uy*DT_;
    *(float4*)&prev[n*4] = npv;
    *(float4*)&prev_st[n*4] = nps;
    *(float4*)&outS[(size_t)n*4] = npv;
    outU[n*2]     = ux;
    outU[n*2 + 1] = uy;
  }
}

// ---------------------------------------------------------------- finalize scalars
__global__ void k_final(const float* __restrict__ ss, float* __restrict__ out) {
  if (threadIdx.x == 0) {
    float t = 0.f;
    for (int i = 0; i < FTS; i++) t += sqrtf(ss[i]);
    out[(size_t)FTS * N_ * 6]     = t / (float)N_;
    out[(size_t)FTS * N_ * 6 + 1] = ss[FTS];
  }
}

// ================================================================ launch
extern "C" void kernel_launch(void* const* d_in, const int* in_sizes, int n_in,
                              void* d_out, int out_size, void* d_ws, size_t ws_size,
                              hipStream_t stream) {
  (void)in_sizes; (void)n_in; (void)out_size; (void)ws_size;
  const float* x_last    = (const float*)d_in[0];
  const float* x_st_last = (const float*)d_in[1];
  const float* hist_enc  = (const float*)d_in[2];
  const float* z         = (const float*)d_in[3];
  const float* node_size = (const float*)d_in[4];
  const float* W_h0 = (const float*)d_in[5];
  const float* b_h0 = (const float*)d_in[6];
  const float* W_c0 = (const float*)d_in[7];
  const float* b_c0 = (const float*)d_in[8];
  const float* W_gh = (const float*)d_in[9];
  const float* b_gh = (const float*)d_in[10];
  const float* W_gih = (const float*)d_in[11];
  const float* W_ghh = (const float*)d_in[12];
  const float* b_gih = (const float*)d_in[13];
  const float* b_ghh = (const float*)d_in[14];
  const float* W_proj = (const float*)d_in[15];
  const float* b_proj = (const float*)d_in[16];
  const float* W_att1 = (const float*)d_in[17];
  const float* W_att2 = (const float*)d_in[18];
  const float* v_att  = (const float*)d_in[19];
  const float* W_lih = (const float*)d_in[20];
  const float* W_lhh = (const float*)d_in[21];
  const float* b_lih = (const float*)d_in[22];
  const float* b_lhh = (const float*)d_in[23];
  const float* W_e1 = (const float*)d_in[24];
  const float* b_e1 = (const float*)d_in[25];
  const float* W_e2 = (const float*)d_in[26];
  const float* b_e2 = (const float*)d_in[27];
  const float* W_a1 = (const float*)d_in[28];
  const float* b_a1 = (const float*)d_in[29];
  const float* W_a2 = (const float*)d_in[30];
  const float* b_a2 = (const float*)d_in[31];
  const int* e1   = (const int*)d_in[32];
  const int* e2   = (const int*)d_in[33];
  const int* nobs = (const int*)d_in[34];
  float* out = (float*)d_out;

  // workspace carve (floats)
  float* wsf     = (float*)d_ws;
  float* prev    = wsf;                     // 32768
  float* prev_st = wsf + 32768;             // 32768
  float* des     = wsf + 65536;             // 196608
  float* ss      = wsf + 262144;            // 16
  float* rad     = wsf + 262160;            // 122880
  float* szf     = wsf + 385040;            // 491520 -> ends 876560
  float* baseA   = wsf + 876560;
  // GRU phase view
  float* gh0 = baseA;
  float* gh1 = baseA + (size_t)N_ * 256;
  float* gi  = baseA + (size_t)2 * N_ * 256;
  // main phase view (aliases GRU-phase buffers, dead by then)
  float* hA   = baseA;
  float* hB   = baseA + (size_t)N_ * 256;
  float* cbuf = baseA + (size_t)2 * N_ * 256;
  float* ctx  = baseA + (size_t)3 * N_ * 256;
  float* rel  = baseA + (size_t)4 * N_ * 256;
  float* nwp  = rel + (size_t)N_ * 4;
  float* nwp2 = nwp + (size_t)N_ * 2;
  unsigned short* wsB = (unsigned short*)(wsf + 9330704);  // 128 frags x2 x512 ushorts = 256KB

  k_zero<<<1, 64, 0, stream>>>(ss);
  k_edge_static<<<(E_ + 255) / 256, 256, 0, stream>>>(e1, e2, node_size, rad, szf);
  k_prep_B<<<32, 256, 0, stream>>>(W_e2, wsB);

  // guide GRU phase
  k_xz_gemm<<<dim3(16, 256), 256, 0, stream>>>(hist_enc, z, W_gh, b_gh, W_gih, b_gih, gh0, gi);
  float* gcur = gh0;
  float* gnxt = gh1;
  for (int t = 0; t < FTS; t++) {
    k_gru<<<dim3(4, 256), 256, 0, stream>>>(gcur, W_ghh, b_ghh, gi, gnxt);
    k_proj<<<N_ / 4, 256, 0, stream>>>(gnxt, W_proj, b_proj, des + (size_t)t * N_ * 2);
    float* tmp = gcur; gcur = gnxt; gnxt = tmp;
  }

  // main rollout
  k_init_hc<<<N_, 256, 0, stream>>>(x_last, x_st_last, W_h0, b_h0, W_c0, b_c0,
                                    hA, cbuf, prev, prev_st);
  float* hcur = hA;
  float* hnxt = hB;
  for (int t = 0; t < FTS; t++) {
    const float* des_t = des + (size_t)t * N_ * 2;
    const float* des_n = des + (size_t)((t + 1 < FTS) ? t + 1 : FTS - 1) * N_ * 2;
    const float* des_p = (t > 0) ? des + (size_t)(t - 1) * N_ * 2 : nullptr;
    k_edge_attn<<<N_ / 4, 256, 0, stream>>>(prev, prev_st, x_st_last, szf, rad,
                                            nobs, e1, e2, W_e1, b_e1, wsB, b_e2,
                                            W_att1, W_att2, v_att,
                                            des_p, des_t, des_n,
                                            rel, nwp, nwp2, ctx, ss + t, ss + 12);
    k_lstm<<<dim3(4, 256), 256, 0, stream>>>(ctx, hcur, W_lih, W_lhh, b_lih, b_lhh,
                                             cbuf, hnxt);
    k_action<<<N_ / 16, 256, 0, stream>>>(hnxt, z, rel, nwp, nwp2,
                                          W_a1, b_a1, W_a2, b_a2,
                                          prev, prev_st,
                                          out + (size_t)t * N_ * 4,
                                          out + (size_t)FTS * N_ * 4 + (size_t)t * N_ * 2);
    float* tmp = hcur; hcur = hnxt; hnxt = tmp;
  }
  k_final<<<1, 64, 0, stream>>>(ss, out);
}

// Round 3
// 3275.428 us; speedup vs baseline: 1.5184x; 1.3955x over previous
//
#include <hip/hip_runtime.h>

#define DEVI __device__ __forceinline__

constexpr int N_  = 8192;
constexpr int K_  = 15;
constexpr int E_  = N_ * K_;     // 122880
constexpr int FTS = 12;
constexpr float DT_ = 0.25f;

typedef __attribute__((ext_vector_type(8))) short short8x;
typedef __attribute__((ext_vector_type(4))) float float4x;

union U8 { unsigned int u[4]; short8x v; };

DEVI float sigf(float x) { return 1.0f / (1.0f + __expf(-x)); }
DEVI unsigned int f2u(float x) { union { float f; unsigned int u; } c; c.f = x; return c.u; }
DEVI float u2f(unsigned int x) { union { unsigned int u; float f; } c; c.u = x; return c.f; }

// split 8 consecutive fp32 into hi/lo bf16 fragments (hi = truncate, lo = exact residual rounded)
DEVI void split8(const float* __restrict__ s, short8x& hi8, short8x& lo8) {
  U8 ph, pl;
#pragma unroll
  for (int p = 0; p < 4; p++) {
    float a0 = s[2*p], a1 = s[2*p+1];
    unsigned int u0 = f2u(a0), u1 = f2u(a1);
    unsigned int h0 = u0 & 0xFFFF0000u, h1 = u1 & 0xFFFF0000u;
    ph.u[p] = (u0 >> 16) | h1;
    float l0 = a0 - u2f(h0), l1 = a1 - u2f(h1);
    pl.u[p] = (f2u(l0) >> 16) | (f2u(l1) & 0xFFFF0000u);
  }
  hi8 = ph.v; lo8 = pl.v;
}

// ---------------------------------------------------------------- zero accum
__global__ void k_zero(float* ss) {
  if (threadIdx.x < 13) ss[threadIdx.x] = 0.f;
}

// ---------------------------------------------------------------- init des to b_proj (bias base for atomics)
__global__ __launch_bounds__(256) void k_init_des(const float* __restrict__ b_proj,
                                                  float* __restrict__ des) {
  int i = blockIdx.x * 256 + threadIdx.x;   // < FTS*N_
  des[i*2]     = b_proj[0];
  des[i*2 + 1] = b_proj[1];
}

// ---------------------------------------------------------------- edge static (rad, size feats)
__global__ __launch_bounds__(256) void k_edge_static(
    const int* __restrict__ e1, const int* __restrict__ e2,
    const float* __restrict__ nsize, float* __restrict__ rad, float* __restrict__ szf)
{
  int e = blockIdx.x * 256 + threadIdx.x;
  if (e >= E_) return;
  int i1 = e1[e], i2 = e2[e];
  float s1x = nsize[i1*2+0], s1y = nsize[i1*2+1];
  float s2x = nsize[i2*2+0], s2y = nsize[i2*2+1];
  rad[e] = 0.5f * (sqrtf(s1x*s1x + s1y*s1y) + sqrtf(s2x*s2x + s2y*s2y));
  *(float4*)&szf[e*4] = make_float4(s1x, s1y, s2x, s2y);
}

// ---------------------------------------------------------------- generic split-bf16 B-fragment prep
// frag fid = ks*NT + nt holds B[k=32ks..+31][n=16nt..+15]; lane L: k0=32ks+(L>>4)*8, n=16nt+(L&15)
// mode 0: vertical concat   (k < split -> WA[k*wA+n], else WB[(k-split)*wB+n])
// mode 1: horizontal concat (n < split -> WA[k*wA+n], else WB[k*wB+(n-split)])
__global__ __launch_bounds__(256) void k_prep(
    const float* __restrict__ WA, const float* __restrict__ WB,
    int mode, int split, int wA, int wB, int Ktot, int NT, int nfrag,
    unsigned short* __restrict__ out)
{
  int t = blockIdx.x * 256 + threadIdx.x;
  int fid = t >> 6, L = t & 63;
  if (fid >= nfrag) return;
  int ks = fid / NT, nt = fid % NT;
  int k0 = ks * 32 + (L >> 4) * 8;
  int n  = nt * 16 + (L & 15);
  unsigned int hi[4], lo[4];
#pragma unroll
  for (int p = 0; p < 4; p++) {
    float w0 = 0.f, w1 = 0.f;
    int ka = k0 + 2*p, kb = ka + 1;
    if (mode == 0) {
      if (ka < Ktot) w0 = (ka < split) ? WA[(size_t)ka*wA + n] : WB[(size_t)(ka-split)*wB + n];
      if (kb < Ktot) w1 = (kb < split) ? WA[(size_t)kb*wA + n] : WB[(size_t)(kb-split)*wB + n];
    } else {
      if (ka < Ktot) w0 = (n < split) ? WA[(size_t)ka*wA + n] : WB[(size_t)ka*wB + (n-split)];
      if (kb < Ktot) w1 = (n < split) ? WA[(size_t)kb*wA + n] : WB[(size_t)kb*wB + (n-split)];
    }
    unsigned int u0 = f2u(w0), u1 = f2u(w1);
    unsigned int h0 = u0 & 0xFFFF0000u, h1 = u1 & 0xFFFF0000u;
    hi[p] = (u0 >> 16) | h1;
    float l0 = w0 - u2f(h0), l1 = w1 - u2f(h1);
    lo[p] = (f2u(l0) >> 16) | (f2u(l1) & 0xFFFF0000u);
  }
  size_t base = (size_t)(fid * 2) * 512 + (size_t)L * 8;
  *(uint4*)(out + base)       = make_uint4(hi[0], hi[1], hi[2], hi[3]);
  *(uint4*)(out + base + 512) = make_uint4(lo[0], lo[1], lo[2], lo[3]);
}

// ================================================================ MFMA GEMM kernels
// Shared structure: block = 64 rows (4 waves x 16) x N-cols; A fp32 staged in LDS
// (stride 36 pad), split to bf16 hi/lo in-register; B from prepped frags.
// lane: m = lane&15 (A-row / C-col), q = lane>>4 (k-quad); C rows = q*4+i.

// ---------------------------------------------------------------- xz GEMM (once): [hist|z] @ [W_gh|W_gih]
__global__ __launch_bounds__(256) void k_xz_mfma(
    const float* __restrict__ hist, const float* __restrict__ z,
    const unsigned short* __restrict__ wB,
    const float* __restrict__ b_gh, const float* __restrict__ b_gih,
    float* __restrict__ gh0, float* __restrict__ gi)
{
  __shared__ __align__(16) float Abuf[64][36];
  const int tid = threadIdx.x;
  const int w = tid >> 6, lane = tid & 63;
  const int m = lane & 15, q = lane >> 4;
  const int n0 = blockIdx.x * 64;
  const int r_ = tid >> 2, c_ = (tid & 3) * 8;
  float4x acc[16];
#pragma unroll
  for (int tl = 0; tl < 16; tl++) acc[tl] = (float4x){0.f,0.f,0.f,0.f};

  for (int ks = 0; ks < 9; ks++) {
    __syncthreads();
    {
      int kk = ks*32 + c_;
      int n = n0 + r_;
      float4 v0, v1;
      if (kk < 256) {
        v0 = *(const float4*)&hist[(size_t)n*256 + kk];
        v1 = *(const float4*)&hist[(size_t)n*256 + kk + 4];
      } else if (kk == 256) {
        v0 = *(const float4*)&z[n*8];
        v1 = *(const float4*)&z[n*8 + 4];
      } else {
        v0 = make_float4(0,0,0,0); v1 = v0;
      }
      *(float4*)&Abuf[r_][c_]     = v0;
      *(float4*)&Abuf[r_][c_ + 4] = v1;
    }
    __syncthreads();
    short8x aHi, aLo;
    split8(&Abuf[w*16 + m][q*8], aHi, aLo);
#pragma unroll
    for (int tl = 0; tl < 16; tl++) {
      int nt = blockIdx.y*16 + tl;
      size_t off = (size_t)((ks*64 + nt)*2) * 512 + (size_t)lane*8;
      short8x bh = *(const short8x*)(wB + off);
      short8x bl = *(const short8x*)(wB + off + 512);
      acc[tl] = __builtin_amdgcn_mfma_f32_16x16x32_bf16(aHi, bl, acc[tl], 0, 0, 0);
      acc[tl] = __builtin_amdgcn_mfma_f32_16x16x32_bf16(aLo, bh, acc[tl], 0, 0, 0);
      acc[tl] = __builtin_amdgcn_mfma_f32_16x16x32_bf16(aHi, bh, acc[tl], 0, 0, 0);
    }
  }
#pragma unroll
  for (int tl = 0; tl < 16; tl++) {
    int col = (blockIdx.y*16 + tl)*16 + m;
    float bias = (col < 256) ? b_gh[col] : b_gih[col - 256];
#pragma unroll
    for (int i = 0; i < 4; i++) {
      int n = n0 + w*16 + q*4 + i;
      float v = acc[tl][i] + bias;
      if (col < 256) gh0[(size_t)n*256 + col] = v;
      else           gi[(size_t)n*768 + col - 256] = v;
    }
  }
}

// ---------------------------------------------------------------- GRU step (MFMA) + fused proj->des
__global__ __launch_bounds__(256) void k_gru_mfma(
    const float* __restrict__ h_in, const unsigned short* __restrict__ wB,
    const float* __restrict__ b_hh, const float* __restrict__ gi,
    const float* __restrict__ W_proj, float* __restrict__ des_t,
    float* __restrict__ h_out)
{
  __shared__ __align__(16) float Abuf[64][36];
  const int tid = threadIdx.x;
  const int w = tid >> 6, lane = tid & 63;
  const int m = lane & 15, q = lane >> 4;
  const int n0 = blockIdx.x * 64;
  const int j0 = blockIdx.y * 64;
  const int r_ = tid >> 2, c_ = (tid & 3) * 8;
  float4x acc[12];
#pragma unroll
  for (int tl = 0; tl < 12; tl++) acc[tl] = (float4x){0.f,0.f,0.f,0.f};

  for (int ks = 0; ks < 8; ks++) {
    __syncthreads();
    {
      int kk = ks*32 + c_;
      int n = n0 + r_;
      *(float4*)&Abuf[r_][c_]     = *(const float4*)&h_in[(size_t)n*256 + kk];
      *(float4*)&Abuf[r_][c_ + 4] = *(const float4*)&h_in[(size_t)n*256 + kk + 4];
    }
    __syncthreads();
    short8x aHi, aLo;
    split8(&Abuf[w*16 + m][q*8], aHi, aLo);
#pragma unroll
    for (int tl = 0; tl < 12; tl++) {
      int g = tl >> 2, jt = tl & 3;
      int nt = g*16 + (j0 >> 4) + jt;
      size_t off = (size_t)((ks*48 + nt)*2) * 512 + (size_t)lane*8;
      short8x bh = *(const short8x*)(wB + off);
      short8x bl = *(const short8x*)(wB + off + 512);
      acc[tl] = __builtin_amdgcn_mfma_f32_16x16x32_bf16(aHi, bl, acc[tl], 0, 0, 0);
      acc[tl] = __builtin_amdgcn_mfma_f32_16x16x32_bf16(aLo, bh, acc[tl], 0, 0, 0);
      acc[tl] = __builtin_amdgcn_mfma_f32_16x16x32_bf16(aHi, bh, acc[tl], 0, 0, 0);
    }
  }
  float pd0[4] = {0,0,0,0}, pd1[4] = {0,0,0,0};
#pragma unroll
  for (int jt = 0; jt < 4; jt++) {
    int j = j0 + jt*16 + m;
    float br = b_hh[j], bz = b_hh[256 + j], bn = b_hh[512 + j];
    float wp0 = W_proj[j*2], wp1 = W_proj[j*2 + 1];
#pragma unroll
    for (int i = 0; i < 4; i++) {
      int n = n0 + w*16 + q*4 + i;
      float ir  = gi[(size_t)n*768 + j];
      float iz  = gi[(size_t)n*768 + 256 + j];
      float inn = gi[(size_t)n*768 + 512 + j];
      float hold = h_in[(size_t)n*256 + j];
      float r = sigf(ir + acc[0*4 + jt][i] + br);
      float u = sigf(iz + acc[1*4 + jt][i] + bz);
      float nh = (1.f - u) * tanhf(inn + r * (acc[2*4 + jt][i] + bn)) + u * hold;
      h_out[(size_t)n*256 + j] = nh;
      pd0[i] += nh * wp0;
      pd1[i] += nh * wp1;
    }
  }
#pragma unroll
  for (int off = 1; off < 16; off <<= 1) {
#pragma unroll
    for (int i = 0; i < 4; i++) {
      pd0[i] += __shfl_xor(pd0[i], off);
      pd1[i] += __shfl_xor(pd1[i], off);
    }
  }
  if (m == 0) {
#pragma unroll
    for (int i = 0; i < 4; i++) {
      int n = n0 + w*16 + q*4 + i;
      atomicAdd(&des_t[n*2],     pd0[i]);
      atomicAdd(&des_t[n*2 + 1], pd1[i]);
    }
  }
}

// ---------------------------------------------------------------- LSTM cell (MFMA)
__global__ __launch_bounds__(256) void k_lstm_mfma(
    const float* __restrict__ ctxg, const float* __restrict__ h_in,
    const unsigned short* __restrict__ wB,
    const float* __restrict__ b_ih, const float* __restrict__ b_hh,
    float* __restrict__ c_st, float* __restrict__ h_out)
{
  __shared__ __align__(16) float Abuf[64][36];
  const int tid = threadIdx.x;
  const int w = tid >> 6, lane = tid & 63;
  const int m = lane & 15, q = lane >> 4;
  const int n0 = blockIdx.x * 64;
  const int j0 = blockIdx.y * 64;
  const int r_ = tid >> 2, c_ = (tid & 3) * 8;
  float4x acc[16];
#pragma unroll
  for (int tl = 0; tl < 16; tl++) acc[tl] = (float4x){0.f,0.f,0.f,0.f};

  for (int ks = 0; ks < 12; ks++) {
    __syncthreads();
    {
      int kk = ks*32 + c_;
      int n = n0 + r_;
      float4 v0, v1;
      if (kk < 128) {
        v0 = *(const float4*)&ctxg[(size_t)n*128 + kk];
        v1 = *(const float4*)&ctxg[(size_t)n*128 + kk + 4];
      } else {
        v0 = *(const float4*)&h_in[(size_t)n*256 + kk - 128];
        v1 = *(const float4*)&h_in[(size_t)n*256 + kk - 124];
      }
      *(float4*)&Abuf[r_][c_]     = v0;
      *(float4*)&Abuf[r_][c_ + 4] = v1;
    }
    __syncthreads();
    short8x aHi, aLo;
    split8(&Abuf[w*16 + m][q*8], aHi, aLo);
#pragma unroll
    for (int tl = 0; tl < 16; tl++) {
      int g = tl >> 2, jt = tl & 3;
      int nt = g*16 + (j0 >> 4) + jt;
      size_t off = (size_t)((ks*64 + nt)*2) * 512 + (size_t)lane*8;
      short8x bh = *(const short8x*)(wB + off);
      short8x bl = *(const short8x*)(wB + off + 512);
      acc[tl] = __builtin_amdgcn_mfma_f32_16x16x32_bf16(aHi, bl, acc[tl], 0, 0, 0);
      acc[tl] = __builtin_amdgcn_mfma_f32_16x16x32_bf16(aLo, bh, acc[tl], 0, 0, 0);
      acc[tl] = __builtin_amdgcn_mfma_f32_16x16x32_bf16(aHi, bh, acc[tl], 0, 0, 0);
    }
  }
#pragma unroll
  for (int jt = 0; jt < 4; jt++) {
    int j = j0 + jt*16 + m;
    float bi = b_ih[j]       + b_hh[j];
    float bf = b_ih[256 + j] + b_hh[256 + j];
    float bg = b_ih[512 + j] + b_hh[512 + j];
    float bo = b_ih[768 + j] + b_hh[768 + j];
#pragma unroll
    for (int i = 0; i < 4; i++) {
      int n = n0 + w*16 + q*4 + i;
      float g_i = sigf(acc[0*4 + jt][i] + bi);
      float g_f = sigf(acc[1*4 + jt][i] + bf);
      float g_g = tanhf(acc[2*4 + jt][i] + bg);
      float g_o = sigf(acc[3*4 + jt][i] + bo);
      float cv = g_f * c_st[(size_t)n*256 + j] + g_i * g_g;
      c_st[(size_t)n*256 + j] = cv;
      h_out[(size_t)n*256 + j] = g_o * tanhf(cv);
    }
  }
}

// ---------------------------------------------------------------- action MLP (MFMA) + layer2 + dynamics
__global__ __launch_bounds__(256) void k_action_mfma(
    const float* __restrict__ h, const float* __restrict__ z,
    const float* __restrict__ rel, const float* __restrict__ nwp, const float* __restrict__ nwp2,
    const unsigned short* __restrict__ wB, const float* __restrict__ b_a1,
    const float* __restrict__ W_a2, const float* __restrict__ b_a2,
    float* __restrict__ prev, float* __restrict__ prev_st,
    float* __restrict__ outS, float* __restrict__ outU)
{
  __shared__ __align__(16) float Abuf[64][36];
  const int tid = threadIdx.x;
  const int w = tid >> 6, lane = tid & 63;
  const int m = lane & 15, q = lane >> 4;
  const int n0 = blockIdx.x * 64;
  const int r_ = tid >> 2, c_ = (tid & 3) * 8;
  float4x acc[16];
#pragma unroll
  for (int tl = 0; tl < 16; tl++) acc[tl] = (float4x){0.f,0.f,0.f,0.f};

  for (int ks = 0; ks < 9; ks++) {
    __syncthreads();
    {
      int kk = ks*32 + c_;
      int n = n0 + r_;
      float4 v0, v1;
      if (kk < 256) {
        v0 = *(const float4*)&h[(size_t)n*256 + kk];
        v1 = *(const float4*)&h[(size_t)n*256 + kk + 4];
      } else if (kk == 256) {
        v0 = *(const float4*)&z[n*8];
        v1 = *(const float4*)&z[n*8 + 4];
      } else if (kk == 264) {
        v0 = *(const float4*)&rel[n*4];
        float2 w1 = *(const float2*)&nwp[n*2];
        float2 w2 = *(const float2*)&nwp2[n*2];
        v1 = make_float4(w1.x, w1.y, w2.x, w2.y);
      } else {
        v0 = make_float4(0,0,0,0); v1 = v0;
      }
      *(float4*)&Abuf[r_][c_]     = v0;
      *(float4*)&Abuf[r_][c_ + 4] = v1;
    }
    __syncthreads();
    short8x aHi, aLo;
    split8(&Abuf[w*16 + m][q*8], aHi, aLo);
#pragma unroll
    for (int tl = 0; tl < 16; tl++) {
      size_t off = (size_t)((ks*16 + tl)*2) * 512 + (size_t)lane*8;
      short8x bh = *(const short8x*)(wB + off);
      short8x bl = *(const short8x*)(wB + off + 512);
      acc[tl] = __builtin_amdgcn_mfma_f32_16x16x32_bf16(aHi, bl, acc[tl], 0, 0, 0);
      acc[tl] = __builtin_amdgcn_mfma_f32_16x16x32_bf16(aLo, bh, acc[tl], 0, 0, 0);
      acc[tl] = __builtin_amdgcn_mfma_f32_16x16x32_bf16(aHi, bh, acc[tl], 0, 0, 0);
    }
  }
  // layer 2: u[n][c] = tanh( sum_j relu(H)[n][j] * W_a2[j][c] + b_a2[c] )
  float p0[4] = {0,0,0,0}, p1[4] = {0,0,0,0};
#pragma unroll
  for (int tl = 0; tl < 16; tl++) {
    int col = tl*16 + m;
    float ba = b_a1[col];
    float2 w2 = *(const float2*)&W_a2[col*2];
#pragma unroll
    for (int i = 0; i < 4; i++) {
      float hv = fmaxf(acc[tl][i] + ba, 0.f);
      p0[i] += hv * w2.x;
      p1[i] += hv * w2.y;
    }
  }
#pragma unroll
  for (int off = 1; off < 16; off <<= 1) {
#pragma unroll
    for (int i = 0; i < 4; i++) {
      p0[i] += __shfl_xor(p0[i], off);
      p1[i] += __shfl_xor(p1[i], off);
    }
  }
  if (m == 0) {
    float ba0 = b_a2[0], ba1 = b_a2[1];
    const float hd = 0.5f * DT_ * DT_;
#pragma unroll
    for (int i = 0; i < 4; i++) {
      int n = n0 + w*16 + q*4 + i;
      float ux = tanhf(p0[i] + ba0);
      float uy = tanhf(p1[i] + ba1);
      float4 pv = *(const float4*)&prev[n*4];
      float4 ps = *(const float4*)&prev_st[n*4];
      float4 npv, nps;
      npv.x = pv.x + pv.z*DT_ + ux*hd;
      npv.y = pv.y + pv.w*DT_ + uy*hd;
      npv.z = pv.z + ux*DT_;
      npv.w = pv.w + uy*DT_;
      nps.x = ps.x + ps.z*DT_ + ux*hd;
      nps.y = ps.y + ps.w*DT_ + uy*hd;
      nps.z = ps.z + ux*DT_;
      nps.w = ps.w + uy*DT_;
      *(float4*)&prev[n*4] = npv;
      *(float4*)&prev_st[n*4] = nps;
      *(float4*)&outS[(size_t)n*4] = npv;
      outU[n*2]     = ux;
      outU[n*2 + 1] = uy;
    }
  }
}

// ---------------------------------------------------------------- LSTM h0/c0 + prev copies
__global__ __launch_bounds__(256) void k_init_hc(
    const float* __restrict__ x_last, const float* __restrict__ x_st_last,
    const float* __restrict__ W_h0, const float* __restrict__ b_h0,
    const float* __restrict__ W_c0, const float* __restrict__ b_c0,
    float* __restrict__ h, float* __restrict__ c,
    float* __restrict__ prev, float* __restrict__ prev_st)
{
  const int n = blockIdx.x;
  const int j = threadIdx.x;
  float x0 = x_st_last[n*4], x1 = x_st_last[n*4+1], x2 = x_st_last[n*4+2], x3 = x_st_last[n*4+3];
  h[(size_t)n*256 + j] = b_h0[j] + x0*W_h0[j] + x1*W_h0[256+j] + x2*W_h0[512+j] + x3*W_h0[768+j];
  c[(size_t)n*256 + j] = b_c0[j] + x0*W_c0[j] + x1*W_c0[256+j] + x2*W_c0[512+j] + x3*W_c0[768+j];
  if (j < 4) prev[n*4 + j] = x_last[n*4 + j];
  else if (j < 8) prev_st[n*4 + (j-4)] = x_st_last[n*4 + (j-4)];
}

// ---------------------------------------------------------------- fused edge-MLP(MFMA) + attention + ctx + ccost/rel/terr
__global__ __launch_bounds__(256, 2) void k_edge_attn(
    const float* __restrict__ prev, const float* __restrict__ prev_st,
    const float* __restrict__ x_st_last,
    const float* __restrict__ szf, const float* __restrict__ rad,
    const int* __restrict__ nobs, const int* __restrict__ e1, const int* __restrict__ e2,
    const float* __restrict__ W_e1, const float* __restrict__ b_e1,
    const unsigned short* __restrict__ wsB, const float* __restrict__ b_e2,
    const float* __restrict__ W_att1, const float* __restrict__ W_att2,
    const float* __restrict__ v_att,
    const float* __restrict__ des_p, const float* __restrict__ des_t,
    const float* __restrict__ des_n,
    float* __restrict__ relg, float* __restrict__ nwp, float* __restrict__ nwp2,
    float* __restrict__ ctx, float* __restrict__ ss_t, float* __restrict__ cc)
{
  __shared__ __align__(16) float smem[12520];
  float* sm_enc   = smem;
  float* sm_feats = smem + 8704;
  float* sm_watt1 = smem + 9216;
  float* sm_sct   = smem + 11264;
  float* sm_flags = smem + 12224;
  float* sm_relv  = smem + 12288;
  float* sm_sck   = smem + 12304;
  float* sm_attw  = smem + 12368;
  float* sm_watt2 = smem + 12432;
  float* sm_vatt  = smem + 12496;
  float* sm_red   = smem + 12512;

  const int n0  = blockIdx.x * 4;
  const int tid = threadIdx.x;
  const int lane = tid & 63;
  const int g    = tid >> 6;

  for (int i = tid; i < 2048; i += 256) sm_watt1[i] = W_att1[i];
  if (tid >= 176 && tid < 192) sm_vatt[tid - 176] = v_att[tid - 176];
  if (tid >= 192) sm_watt2[tid - 192] = W_att2[tid - 192];

  if (tid < 64) {
    float v = 0.f;
    if (tid < 60) {
      int gg = tid / 15, k = tid % 15;
      int idx = nobs[(n0 + gg) * 15 + k];
      float f[8] = {0,0,0,0,0,0,0,0};
      float fl = 0.f;
      if (idx > 0) {
        int e = idx - 1;
        int i1 = e1[e], i2 = e2[e];
#pragma unroll
        for (int d = 0; d < 4; d++) f[d] = prev[i2*4 + d] - prev[i1*4 + d];
        float4 sz = *(const float4*)&szf[(size_t)e*4];
        f[4] = sz.x; f[5] = sz.y; f[6] = sz.z; f[7] = sz.w;
        fl = 1.f;
        float dist = sqrtf(f[0]*f[0] + f[1]*f[1]);
        v = fmaxf(rad[e] - dist, 0.f);
      }
#pragma unroll
      for (int d = 0; d < 8; d++) sm_feats[(gg*16 + k)*8 + d] = f[d];
      sm_flags[gg*16 + k] = fl;
    } else {
      int gg = tid - 60;
#pragma unroll
      for (int d = 0; d < 8; d++) sm_feats[(gg*16 + 15)*8 + d] = 0.f;
      sm_flags[gg*16 + 15] = 0.f;
    }
#pragma unroll
    for (int off = 32; off; off >>= 1) v += __shfl_down(v, off);
    if (tid == 0) atomicAdd(cc, v);
  } else if (tid < 68) {
    int gg = tid - 64;
    int n = n0 + gg;
    float4 ps = *(const float4*)&prev_st[n*4];
    float r0, r1, r2, r3;
    if (des_p) {
      float4 xs = *(const float4*)&x_st_last[n*4];
      r0 = ps.x - xs.x - des_p[n*2];
      r1 = ps.y - xs.y - des_p[n*2 + 1];
      r2 = ps.z - xs.z;
      r3 = ps.w - xs.w;
    } else { r0 = ps.x; r1 = ps.y; r2 = ps.z; r3 = ps.w; }
    sm_relv[gg*4+0] = r0; sm_relv[gg*4+1] = r1; sm_relv[gg*4+2] = r2; sm_relv[gg*4+3] = r3;
    *(float4*)&relg[n*4] = make_float4(r0, r1, r2, r3);
    nwp[n*2]      = des_t[n*2]     - ps.x;
    nwp[n*2 + 1]  = des_t[n*2 + 1] - ps.y;
    nwp2[n*2]     = des_n[n*2]     - ps.x;
    nwp2[n*2 + 1] = des_n[n*2 + 1] - ps.y;
    sm_red[gg] = r0*r0 + r1*r1;
  }
  __syncthreads();
  if (tid == 64) atomicAdd(ss_t, sm_red[0] + sm_red[1] + sm_red[2] + sm_red[3]);

  const int q = lane >> 4, m = lane & 15;
  float f[8];
  {
    const float4 fa = *(const float4*)&sm_feats[(g*16 + m)*8];
    const float4 fb = *(const float4*)&sm_feats[(g*16 + m)*8 + 4];
    f[0]=fa.x; f[1]=fa.y; f[2]=fa.z; f[3]=fa.w; f[4]=fb.x; f[5]=fb.y; f[6]=fb.z; f[7]=fb.w;
  }
  short8x aHi[8], aLo[8];
  const float4* We14 = (const float4*)W_e1;
  const float4* Be14 = (const float4*)b_e1;
#pragma unroll
  for (int ks = 0; ks < 8; ks++) {
    float h[8];
    {
      float4 b0 = Be14[8*ks + 2*q];
      float4 b1 = Be14[8*ks + 2*q + 1];
      h[0]=b0.x; h[1]=b0.y; h[2]=b0.z; h[3]=b0.w; h[4]=b1.x; h[5]=b1.y; h[6]=b1.z; h[7]=b1.w;
    }
#pragma unroll
    for (int d = 0; d < 8; d++) {
      float4 wa = We14[d*64 + ks*8 + 2*q];
      float4 wb = We14[d*64 + ks*8 + 2*q + 1];
      h[0] += f[d]*wa.x; h[1] += f[d]*wa.y; h[2] += f[d]*wa.z; h[3] += f[d]*wa.w;
      h[4] += f[d]*wb.x; h[5] += f[d]*wb.y; h[6] += f[d]*wb.z; h[7] += f[d]*wb.w;
    }
    U8 ph, pl;
#pragma unroll
    for (int p = 0; p < 4; p++) {
      float a0 = fmaxf(h[2*p], 0.f), a1 = fmaxf(h[2*p+1], 0.f);
      unsigned int u0 = f2u(a0), u1 = f2u(a1);
      unsigned int h0 = u0 & 0xFFFF0000u, h1 = u1 & 0xFFFF0000u;
      ph.u[p] = (u0 >> 16) | h1;
      float l0 = a0 - u2f(h0), l1 = a1 - u2f(h1);
      pl.u[p] = (f2u(l0) >> 16) | (f2u(l1) & 0xFFFF0000u);
    }
    aHi[ks] = ph.v;
    aLo[ks] = pl.v;
  }

#pragma unroll
  for (int nt = 0; nt < 8; nt++) {
    float4x acc = {0.f, 0.f, 0.f, 0.f};
#pragma unroll
    for (int ks = 0; ks < 8; ks++) {
      size_t off = (size_t)((ks*8 + nt)*2) * 512 + (size_t)lane * 8;
      short8x bh = *(const short8x*)(wsB + off);
      short8x bl = *(const short8x*)(wsB + off + 512);
      acc = __builtin_amdgcn_mfma_f32_16x16x32_bf16(aHi[ks], bl, acc, 0, 0, 0);
      acc = __builtin_amdgcn_mfma_f32_16x16x32_bf16(aLo[ks], bh, acc, 0, 0, 0);
      acc = __builtin_amdgcn_mfma_f32_16x16x32_bf16(aHi[ks], bh, acc, 0, 0, 0);
    }
    int col = nt*16 + m;
    float b2 = b_e2[col];
#pragma unroll
    for (int i = 0; i < 4; i++) {
      int r = q*4 + i;
      sm_enc[(g*16 + r)*136 + col] = (acc[i] + b2) * sm_flags[g*16 + r];
    }
  }
  __syncthreads();

  for (int id = tid; id < 960; id += 256) {
    int gg = id / 240;
    int rm = id % 240;
    int k = rm >> 4;
    int a = rm & 15;
    float s = sm_relv[gg*4+0]*sm_watt2[a] + sm_relv[gg*4+1]*sm_watt2[16+a]
            + sm_relv[gg*4+2]*sm_watt2[32+a] + sm_relv[gg*4+3]*sm_watt2[48+a];
    const float4* er = (const float4*)&sm_enc[(gg*16 + k)*136];
#pragma unroll 8
    for (int c4 = 0; c4 < 32; c4++) {
      float4 e = er[c4];
      int cb = c4*4;
      s += e.x * sm_watt1[(cb+0)*16 + a];
      s += e.y * sm_watt1[(cb+1)*16 + a];
      s += e.z * sm_watt1[(cb+2)*16 + a];
      s += e.w * sm_watt1[(cb+3)*16 + a];
    }
    sm_sct[(gg*15 + k)*16 + a] = tanhf(s) * sm_vatt[a];
  }
  __syncthreads();
  if (tid < 60) {
    int gg = tid / 15, k = tid % 15;
    const float4* sp = (const float4*)&sm_sct[(gg*15 + k)*16];
    float4 s0 = sp[0], s1 = sp[1], s2 = sp[2], s3 = sp[3];
    sm_sck[gg*16 + k] = s0.x+s0.y+s0.z+s0.w + s1.x+s1.y+s1.z+s1.w
                      + s2.x+s2.y+s2.z+s2.w + s3.x+s3.y+s3.z+s3.w;
  }
  __syncthreads();
  if (tid < 4) {
    float sc[15], mx = -1e30f;
#pragma unroll
    for (int k = 0; k < 15; k++) { sc[k] = sm_sck[tid*16 + k]; mx = fmaxf(mx, sc[k]); }
    float sum = 0.f;
#pragma unroll
    for (int k = 0; k < 15; k++) { sc[k] = __expf(sc[k] - mx); sum += sc[k]; }
    float inv = 1.f / sum;
#pragma unroll
    for (int k = 0; k < 15; k++) sm_attw[tid*16 + k] = sc[k] * inv;
  }
  __syncthreads();
#pragma unroll
  for (int rep = 0; rep < 2; rep++) {
    int gg = rep*2 + (tid >> 7);
    int c = tid & 127;
    float v = 0.f;
#pragma unroll
    for (int k = 0; k < 15; k++) v += sm_attw[gg*16 + k] * sm_enc[(gg*16 + k)*136 + c];
    ctx[(size_t)(n0 + gg)*128 + c] = v;
  }
}

// ---------------------------------------------------------------- finalize scalars
__global__ void k_final(const float* __restrict__ ss, float* __restrict__ out) {
  if (threadIdx.x == 0) {
    float t = 0.f;
    for (int i = 0; i < FTS; i++) t += sqrtf(ss[i]);
    out[(size_t)FTS * N_ * 6]     = t / (float)N_;
    out[(size_t)FTS * N_ * 6 + 1] = ss[FTS];
  }
}

// ================================================================ launch
extern "C" void kernel_launch(void* const* d_in, const int* in_sizes, int n_in,
                              void* d_out, int out_size, void* d_ws, size_t ws_size,
                              hipStream_t stream) {
  (void)in_sizes; (void)n_in; (void)out_size; (void)ws_size;
  const float* x_last    = (const float*)d_in[0];
  const float* x_st_last = (const float*)d_in[1];
  const float* hist_enc  = (const float*)d_in[2];
  const float* z         = (const float*)d_in[3];
  const float* node_size = (const float*)d_in[4];
  const float* W_h0 = (const float*)d_in[5];
  const float* b_h0 = (const float*)d_in[6];
  const float* W_c0 = (const float*)d_in[7];
  const float* b_c0 = (const float*)d_in[8];
  const float* W_gh = (const float*)d_in[9];
  const float* b_gh = (const float*)d_in[10];
  const float* W_gih = (const float*)d_in[11];
  const float* W_ghh = (const float*)d_in[12];
  const float* b_gih = (const float*)d_in[13];
  const float* b_ghh = (const float*)d_in[14];
  const float* W_proj = (const float*)d_in[15];
  const float* b_proj = (const float*)d_in[16];
  const float* W_att1 = (const float*)d_in[17];
  const float* W_att2 = (const float*)d_in[18];
  const float* v_att  = (const float*)d_in[19];
  const float* W_lih = (const float*)d_in[20];
  const float* W_lhh = (const float*)d_in[21];
  const float* b_lih = (const float*)d_in[22];
  const float* b_lhh = (const float*)d_in[23];
  const float* W_e1 = (const float*)d_in[24];
  const float* b_e1 = (const float*)d_in[25];
  const float* W_e2 = (const float*)d_in[26];
  const float* b_e2 = (const float*)d_in[27];
  const float* W_a1 = (const float*)d_in[28];
  const float* b_a1 = (const float*)d_in[29];
  const float* W_a2 = (const float*)d_in[30];
  const float* b_a2 = (const float*)d_in[31];
  const int* e1   = (const int*)d_in[32];
  const int* e2   = (const int*)d_in[33];
  const int* nobs = (const int*)d_in[34];
  float* out = (float*)d_out;

  // workspace carve (floats)
  float* wsf     = (float*)d_ws;
  float* prev    = wsf;                     // 32768
  float* prev_st = wsf + 32768;             // 32768
  float* des     = wsf + 65536;             // 196608
  float* ss      = wsf + 262144;            // 16
  float* rad     = wsf + 262160;            // 122880
  float* szf     = wsf + 385040;            // 491520 -> end 876560
  float* baseA   = wsf + 876560;            // union region, 10485760 floats -> end 11362320
  // GRU phase view
  float* gh0 = baseA;
  float* gh1 = baseA + (size_t)N_ * 256;
  float* gi  = baseA + (size_t)2 * N_ * 256;
  // main phase view (aliases GRU-phase buffers, dead by then)
  float* hA   = baseA;
  float* hB   = baseA + (size_t)N_ * 256;
  float* cbuf = baseA + (size_t)2 * N_ * 256;
  float* ctx  = baseA + (size_t)3 * N_ * 256;
  float* rel  = baseA + (size_t)4 * N_ * 256;
  float* nwp  = rel + (size_t)N_ * 4;
  float* nwp2 = nwp + (size_t)N_ * 2;
  // prepped B fragments — AFTER the full union region (R2 had these overlapping gi!)
  unsigned short* wsBe = (unsigned short*)(wsf + 11362320);  //  64 frags ( 65536 sh)
  unsigned short* wsBg = (unsigned short*)(wsf + 11427856);  // 384 frags (393216 sh)
  unsigned short* wsBl = (unsigned short*)(wsf + 11624464);  // 768 frags (786432 sh)
  unsigned short* wsBx = (unsigned short*)(wsf + 12017680);  // 576 frags (589824 sh)
  unsigned short* wsBa = (unsigned short*)(wsf + 12312592);  // 144 frags (147456 sh) -> end 12386320 fl

  k_zero<<<1, 64, 0, stream>>>(ss);
  k_edge_static<<<(E_ + 255) / 256, 256, 0, stream>>>(e1, e2, node_size, rad, szf);
  k_init_des<<<FTS * N_ / 256, 256, 0, stream>>>(b_proj, des);

  k_prep<<<16,  256, 0, stream>>>(W_e2,  W_e2,  0, 256, 128,  128,  256, 8,  64,  wsBe);
  k_prep<<<96,  256, 0, stream>>>(W_ghh, W_ghh, 0, 256, 768,  768,  256, 48, 384, wsBg);
  k_prep<<<192, 256, 0, stream>>>(W_lih, W_lhh, 0, 128, 1024, 1024, 384, 64, 768, wsBl);
  k_prep<<<144, 256, 0, stream>>>(W_gh,  W_gih, 1, 256, 256,  768,  264, 64, 576, wsBx);
  k_prep<<<36,  256, 0, stream>>>(W_a1,  W_a1,  0, 272, 256,  256,  272, 16, 144, wsBa);

  // guide GRU phase
  k_xz_mfma<<<dim3(128, 4), 256, 0, stream>>>(hist_enc, z, wsBx, b_gh, b_gih, gh0, gi);
  float* gcur = gh0;
  float* gnxt = gh1;
  for (int t = 0; t < FTS; t++) {
    k_gru_mfma<<<dim3(128, 4), 256, 0, stream>>>(gcur, wsBg, b_ghh, gi, W_proj,
                                                 des + (size_t)t * N_ * 2, gnxt);
    float* tmp = gcur; gcur = gnxt; gnxt = tmp;
  }

  // main rollout
  k_init_hc<<<N_, 256, 0, stream>>>(x_last, x_st_last, W_h0, b_h0, W_c0, b_c0,
                                    hA, cbuf, prev, prev_st);
  float* hcur = hA;
  float* hnxt = hB;
  for (int t = 0; t < FTS; t++) {
    const float* des_t = des + (size_t)t * N_ * 2;
    const float* des_n = des + (size_t)((t + 1 < FTS) ? t + 1 : FTS - 1) * N_ * 2;
    const float* des_p = (t > 0) ? des + (size_t)(t - 1) * N_ * 2 : nullptr;
    k_edge_attn<<<N_ / 4, 256, 0, stream>>>(prev, prev_st, x_st_last, szf, rad,
                                            nobs, e1, e2, W_e1, b_e1, wsBe, b_e2,
                                            W_att1, W_att2, v_att,
                                            des_p, des_t, des_n,
                                            rel, nwp, nwp2, ctx, ss + t, ss + 12);
    k_lstm_mfma<<<dim3(128, 4), 256, 0, stream>>>(ctx, hcur, wsBl, b_lih, b_lhh,
                                                  cbuf, hnxt);
    k_action_mfma<<<128, 256, 0, stream>>>(hnxt, z, rel, nwp, nwp2,
                                           wsBa, b_a1, W_a2, b_a2,
                                           prev, prev_st,
                                           out + (size_t)t * N_ * 4,
                                           out + (size_t)FTS * N_ * 4 + (size_t)t * N_ * 2);
    float* tmp = hcur; hcur = hnxt; hnxt = tmp;
  }
  k_final<<<1, 64, 0, stream>>>(ss, out);
}

// Round 4
// 3089.697 us; speedup vs baseline: 1.6097x; 1.0601x over previous
//
#include <hip/hip_runtime.h>

#define DEVI __device__ __forceinline__

constexpr int N_  = 8192;
constexpr int K_  = 15;
constexpr int E_  = N_ * K_;     // 122880
constexpr int FTS = 12;
constexpr float DT_ = 0.25f;

typedef __attribute__((ext_vector_type(8))) short short8x;
typedef __attribute__((ext_vector_type(4))) float float4x;

union U8 { unsigned int u[4]; short8x v; };

DEVI float sigf(float x) { return 1.0f / (1.0f + __expf(-x)); }
DEVI float tanhf_fast(float x) { float e = __expf(2.f * x); return 1.f - 2.f / (e + 1.f); }
DEVI unsigned int f2u(float x) { union { float f; unsigned int u; } c; c.f = x; return c.u; }
DEVI float u2f(unsigned int x) { union { unsigned int u; float f; } c; c.u = x; return c.f; }

// split 8 consecutive fp32 into hi/lo bf16 fragments (hi = truncate, lo = exact residual rounded)
DEVI void split8(const float* __restrict__ s, short8x& hi8, short8x& lo8) {
  U8 ph, pl;
#pragma unroll
  for (int p = 0; p < 4; p++) {
    float a0 = s[2*p], a1 = s[2*p+1];
    unsigned int u0 = f2u(a0), u1 = f2u(a1);
    unsigned int h0 = u0 & 0xFFFF0000u, h1 = u1 & 0xFFFF0000u;
    ph.u[p] = (u0 >> 16) | h1;
    float l0 = a0 - u2f(h0), l1 = a1 - u2f(h1);
    pl.u[p] = (f2u(l0) >> 16) | (f2u(l1) & 0xFFFF0000u);
  }
  hi8 = ph.v; lo8 = pl.v;
}

// ---------------------------------------------------------------- zero accum
__global__ void k_zero(float* ss) {
  if (threadIdx.x < 13) ss[threadIdx.x] = 0.f;
}

// ---------------------------------------------------------------- init des to b_proj (bias base for atomics)
__global__ __launch_bounds__(256) void k_init_des(const float* __restrict__ b_proj,
                                                  float* __restrict__ des) {
  int i = blockIdx.x * 256 + threadIdx.x;   // < FTS*N_
  des[i*2]     = b_proj[0];
  des[i*2 + 1] = b_proj[1];
}

// ---------------------------------------------------------------- edge static (rad, size feats)
__global__ __launch_bounds__(256) void k_edge_static(
    const int* __restrict__ e1, const int* __restrict__ e2,
    const float* __restrict__ nsize, float* __restrict__ rad, float* __restrict__ szf)
{
  int e = blockIdx.x * 256 + threadIdx.x;
  if (e >= E_) return;
  int i1 = e1[e], i2 = e2[e];
  float s1x = nsize[i1*2+0], s1y = nsize[i1*2+1];
  float s2x = nsize[i2*2+0], s2y = nsize[i2*2+1];
  rad[e] = 0.5f * (sqrtf(s1x*s1x + s1y*s1y) + sqrtf(s2x*s2x + s2y*s2y));
  *(float4*)&szf[e*4] = make_float4(s1x, s1y, s2x, s2y);
}

// ---------------------------------------------------------------- transpose W_att1 -> [a][chan]
__global__ __launch_bounds__(256) void k_prep_attT(const float* __restrict__ W_att1,
                                                   float* __restrict__ wT) {
  int i = blockIdx.x * 256 + threadIdx.x;   // < 2048
  int chan = i >> 4, a = i & 15;
  wT[a * 128 + chan] = W_att1[i];
}

// ---------------------------------------------------------------- generic split-bf16 B-fragment prep
__global__ __launch_bounds__(256) void k_prep(
    const float* __restrict__ WA, const float* __restrict__ WB,
    int mode, int split, int wA, int wB, int Ktot, int NT, int nfrag,
    unsigned short* __restrict__ out)
{
  int t = blockIdx.x * 256 + threadIdx.x;
  int fid = t >> 6, L = t & 63;
  if (fid >= nfrag) return;
  int ks = fid / NT, nt = fid % NT;
  int k0 = ks * 32 + (L >> 4) * 8;
  int n  = nt * 16 + (L & 15);
  unsigned int hi[4], lo[4];
#pragma unroll
  for (int p = 0; p < 4; p++) {
    float w0 = 0.f, w1 = 0.f;
    int ka = k0 + 2*p, kb = ka + 1;
    if (mode == 0) {
      if (ka < Ktot) w0 = (ka < split) ? WA[(size_t)ka*wA + n] : WB[(size_t)(ka-split)*wB + n];
      if (kb < Ktot) w1 = (kb < split) ? WA[(size_t)kb*wA + n] : WB[(size_t)(kb-split)*wB + n];
    } else {
      if (ka < Ktot) w0 = (n < split) ? WA[(size_t)ka*wA + n] : WB[(size_t)ka*wB + (n-split)];
      if (kb < Ktot) w1 = (n < split) ? WA[(size_t)kb*wA + n] : WB[(size_t)kb*wB + (n-split)];
    }
    unsigned int u0 = f2u(w0), u1 = f2u(w1);
    unsigned int h0 = u0 & 0xFFFF0000u, h1 = u1 & 0xFFFF0000u;
    hi[p] = (u0 >> 16) | h1;
    float l0 = w0 - u2f(h0), l1 = w1 - u2f(h1);
    lo[p] = (f2u(l0) >> 16) | (f2u(l1) & 0xFFFF0000u);
  }
  size_t base = (size_t)(fid * 2) * 512 + (size_t)L * 8;
  *(uint4*)(out + base)       = make_uint4(hi[0], hi[1], hi[2], hi[3]);
  *(uint4*)(out + base + 512) = make_uint4(lo[0], lo[1], lo[2], lo[3]);
}

// ================================================================ MFMA GEMM kernels

// ---------------------------------------------------------------- xz GEMM (once): [hist|z] @ [W_gh|W_gih]
__global__ __launch_bounds__(256) void k_xz_mfma(
    const float* __restrict__ hist, const float* __restrict__ z,
    const unsigned short* __restrict__ wB,
    const float* __restrict__ b_gh, const float* __restrict__ b_gih,
    float* __restrict__ gh0, float* __restrict__ gi)
{
  __shared__ __align__(16) float Abuf[64][36];
  const int tid = threadIdx.x;
  const int w = tid >> 6, lane = tid & 63;
  const int m = lane & 15, q = lane >> 4;
  const int n0 = blockIdx.x * 64;
  const int r_ = tid >> 2, c_ = (tid & 3) * 8;
  float4x acc[16];
#pragma unroll
  for (int tl = 0; tl < 16; tl++) acc[tl] = (float4x){0.f,0.f,0.f,0.f};

  for (int ks = 0; ks < 9; ks++) {
    __syncthreads();
    {
      int kk = ks*32 + c_;
      int n = n0 + r_;
      float4 v0, v1;
      if (kk < 256) {
        v0 = *(const float4*)&hist[(size_t)n*256 + kk];
        v1 = *(const float4*)&hist[(size_t)n*256 + kk + 4];
      } else if (kk == 256) {
        v0 = *(const float4*)&z[n*8];
        v1 = *(const float4*)&z[n*8 + 4];
      } else {
        v0 = make_float4(0,0,0,0); v1 = v0;
      }
      *(float4*)&Abuf[r_][c_]     = v0;
      *(float4*)&Abuf[r_][c_ + 4] = v1;
    }
    __syncthreads();
    short8x aHi, aLo;
    split8(&Abuf[w*16 + m][q*8], aHi, aLo);
#pragma unroll
    for (int tl = 0; tl < 16; tl++) {
      int nt = blockIdx.y*16 + tl;
      size_t off = (size_t)((ks*64 + nt)*2) * 512 + (size_t)lane*8;
      short8x bh = *(const short8x*)(wB + off);
      short8x bl = *(const short8x*)(wB + off + 512);
      acc[tl] = __builtin_amdgcn_mfma_f32_16x16x32_bf16(aHi, bl, acc[tl], 0, 0, 0);
      acc[tl] = __builtin_amdgcn_mfma_f32_16x16x32_bf16(aLo, bh, acc[tl], 0, 0, 0);
      acc[tl] = __builtin_amdgcn_mfma_f32_16x16x32_bf16(aHi, bh, acc[tl], 0, 0, 0);
    }
  }
#pragma unroll
  for (int tl = 0; tl < 16; tl++) {
    int col = (blockIdx.y*16 + tl)*16 + m;
    float bias = (col < 256) ? b_gh[col] : b_gih[col - 256];
#pragma unroll
    for (int i = 0; i < 4; i++) {
      int n = n0 + w*16 + q*4 + i;
      float v = acc[tl][i] + bias;
      if (col < 256) gh0[(size_t)n*256 + col] = v;
      else           gi[(size_t)n*768 + col - 256] = v;
    }
  }
}

// ---------------------------------------------------------------- GRU step (MFMA) + fused proj->des
__global__ __launch_bounds__(256) void k_gru_mfma(
    const float* __restrict__ h_in, const unsigned short* __restrict__ wB,
    const float* __restrict__ b_hh, const float* __restrict__ gi,
    const float* __restrict__ W_proj, float* __restrict__ des_t,
    float* __restrict__ h_out)
{
  __shared__ __align__(16) float Abuf[64][36];
  const int tid = threadIdx.x;
  const int w = tid >> 6, lane = tid & 63;
  const int m = lane & 15, q = lane >> 4;
  const int n0 = blockIdx.x * 64;
  const int j0 = blockIdx.y * 64;
  const int r_ = tid >> 2, c_ = (tid & 3) * 8;
  float4x acc[12];
#pragma unroll
  for (int tl = 0; tl < 12; tl++) acc[tl] = (float4x){0.f,0.f,0.f,0.f};

  for (int ks = 0; ks < 8; ks++) {
    __syncthreads();
    {
      int kk = ks*32 + c_;
      int n = n0 + r_;
      *(float4*)&Abuf[r_][c_]     = *(const float4*)&h_in[(size_t)n*256 + kk];
      *(float4*)&Abuf[r_][c_ + 4] = *(const float4*)&h_in[(size_t)n*256 + kk + 4];
    }
    __syncthreads();
    short8x aHi, aLo;
    split8(&Abuf[w*16 + m][q*8], aHi, aLo);
#pragma unroll
    for (int tl = 0; tl < 12; tl++) {
      int g = tl >> 2, jt = tl & 3;
      int nt = g*16 + (j0 >> 4) + jt;
      size_t off = (size_t)((ks*48 + nt)*2) * 512 + (size_t)lane*8;
      short8x bh = *(const short8x*)(wB + off);
      short8x bl = *(const short8x*)(wB + off + 512);
      acc[tl] = __builtin_amdgcn_mfma_f32_16x16x32_bf16(aHi, bl, acc[tl], 0, 0, 0);
      acc[tl] = __builtin_amdgcn_mfma_f32_16x16x32_bf16(aLo, bh, acc[tl], 0, 0, 0);
      acc[tl] = __builtin_amdgcn_mfma_f32_16x16x32_bf16(aHi, bh, acc[tl], 0, 0, 0);
    }
  }
  float pd0[4] = {0,0,0,0}, pd1[4] = {0,0,0,0};
#pragma unroll
  for (int jt = 0; jt < 4; jt++) {
    int j = j0 + jt*16 + m;
    float br = b_hh[j], bz = b_hh[256 + j], bn = b_hh[512 + j];
    float wp0 = W_proj[j*2], wp1 = W_proj[j*2 + 1];
#pragma unroll
    for (int i = 0; i < 4; i++) {
      int n = n0 + w*16 + q*4 + i;
      float ir  = gi[(size_t)n*768 + j];
      float iz  = gi[(size_t)n*768 + 256 + j];
      float inn = gi[(size_t)n*768 + 512 + j];
      float hold = h_in[(size_t)n*256 + j];
      float r = sigf(ir + acc[0*4 + jt][i] + br);
      float u = sigf(iz + acc[1*4 + jt][i] + bz);
      float nh = (1.f - u) * tanhf_fast(inn + r * (acc[2*4 + jt][i] + bn)) + u * hold;
      h_out[(size_t)n*256 + j] = nh;
      pd0[i] += nh * wp0;
      pd1[i] += nh * wp1;
    }
  }
#pragma unroll
  for (int off = 1; off < 16; off <<= 1) {
#pragma unroll
    for (int i = 0; i < 4; i++) {
      pd0[i] += __shfl_xor(pd0[i], off);
      pd1[i] += __shfl_xor(pd1[i], off);
    }
  }
  if (m == 0) {
#pragma unroll
    for (int i = 0; i < 4; i++) {
      int n = n0 + w*16 + q*4 + i;
      atomicAdd(&des_t[n*2],     pd0[i]);
      atomicAdd(&des_t[n*2 + 1], pd1[i]);
    }
  }
}

// ---------------------------------------------------------------- LSTM cell (MFMA)
__global__ __launch_bounds__(256) void k_lstm_mfma(
    const float* __restrict__ ctxg, const float* __restrict__ h_in,
    const unsigned short* __restrict__ wB,
    const float* __restrict__ b_ih, const float* __restrict__ b_hh,
    float* __restrict__ c_st, float* __restrict__ h_out)
{
  __shared__ __align__(16) float Abuf[64][36];
  const int tid = threadIdx.x;
  const int w = tid >> 6, lane = tid & 63;
  const int m = lane & 15, q = lane >> 4;
  const int n0 = blockIdx.x * 64;
  const int j0 = blockIdx.y * 64;
  const int r_ = tid >> 2, c_ = (tid & 3) * 8;
  float4x acc[16];
#pragma unroll
  for (int tl = 0; tl < 16; tl++) acc[tl] = (float4x){0.f,0.f,0.f,0.f};

  for (int ks = 0; ks < 12; ks++) {
    __syncthreads();
    {
      int kk = ks*32 + c_;
      int n = n0 + r_;
      float4 v0, v1;
      if (kk < 128) {
        v0 = *(const float4*)&ctxg[(size_t)n*128 + kk];
        v1 = *(const float4*)&ctxg[(size_t)n*128 + kk + 4];
      } else {
        v0 = *(const float4*)&h_in[(size_t)n*256 + kk - 128];
        v1 = *(const float4*)&h_in[(size_t)n*256 + kk - 124];
      }
      *(float4*)&Abuf[r_][c_]     = v0;
      *(float4*)&Abuf[r_][c_ + 4] = v1;
    }
    __syncthreads();
    short8x aHi, aLo;
    split8(&Abuf[w*16 + m][q*8], aHi, aLo);
#pragma unroll
    for (int tl = 0; tl < 16; tl++) {
      int g = tl >> 2, jt = tl & 3;
      int nt = g*16 + (j0 >> 4) + jt;
      size_t off = (size_t)((ks*64 + nt)*2) * 512 + (size_t)lane*8;
      short8x bh = *(const short8x*)(wB + off);
      short8x bl = *(const short8x*)(wB + off + 512);
      acc[tl] = __builtin_amdgcn_mfma_f32_16x16x32_bf16(aHi, bl, acc[tl], 0, 0, 0);
      acc[tl] = __builtin_amdgcn_mfma_f32_16x16x32_bf16(aLo, bh, acc[tl], 0, 0, 0);
      acc[tl] = __builtin_amdgcn_mfma_f32_16x16x32_bf16(aHi, bh, acc[tl], 0, 0, 0);
    }
  }
#pragma unroll
  for (int jt = 0; jt < 4; jt++) {
    int j = j0 + jt*16 + m;
    float bi = b_ih[j]       + b_hh[j];
    float bf = b_ih[256 + j] + b_hh[256 + j];
    float bg = b_ih[512 + j] + b_hh[512 + j];
    float bo = b_ih[768 + j] + b_hh[768 + j];
#pragma unroll
    for (int i = 0; i < 4; i++) {
      int n = n0 + w*16 + q*4 + i;
      float g_i = sigf(acc[0*4 + jt][i] + bi);
      float g_f = sigf(acc[1*4 + jt][i] + bf);
      float g_g = tanhf_fast(acc[2*4 + jt][i] + bg);
      float g_o = sigf(acc[3*4 + jt][i] + bo);
      float cv = g_f * c_st[(size_t)n*256 + j] + g_i * g_g;
      c_st[(size_t)n*256 + j] = cv;
      h_out[(size_t)n*256 + j] = g_o * tanhf_fast(cv);
    }
  }
}

// ---------------------------------------------------------------- action MLP (MFMA) + layer2 + dynamics
__global__ __launch_bounds__(256) void k_action_mfma(
    const float* __restrict__ h, const float* __restrict__ z,
    const float* __restrict__ rel, const float* __restrict__ nwp, const float* __restrict__ nwp2,
    const unsigned short* __restrict__ wB, const float* __restrict__ b_a1,
    const float* __restrict__ W_a2, const float* __restrict__ b_a2,
    float* __restrict__ prev, float* __restrict__ prev_st,
    float* __restrict__ outS, float* __restrict__ outU)
{
  __shared__ __align__(16) float Abuf[64][36];
  const int tid = threadIdx.x;
  const int w = tid >> 6, lane = tid & 63;
  const int m = lane & 15, q = lane >> 4;
  const int n0 = blockIdx.x * 64;
  const int r_ = tid >> 2, c_ = (tid & 3) * 8;
  float4x acc[16];
#pragma unroll
  for (int tl = 0; tl < 16; tl++) acc[tl] = (float4x){0.f,0.f,0.f,0.f};

  for (int ks = 0; ks < 9; ks++) {
    __syncthreads();
    {
      int kk = ks*32 + c_;
      int n = n0 + r_;
      float4 v0, v1;
      if (kk < 256) {
        v0 = *(const float4*)&h[(size_t)n*256 + kk];
        v1 = *(const float4*)&h[(size_t)n*256 + kk + 4];
      } else if (kk == 256) {
        v0 = *(const float4*)&z[n*8];
        v1 = *(const float4*)&z[n*8 + 4];
      } else if (kk == 264) {
        v0 = *(const float4*)&rel[n*4];
        float2 w1 = *(const float2*)&nwp[n*2];
        float2 w2 = *(const float2*)&nwp2[n*2];
        v1 = make_float4(w1.x, w1.y, w2.x, w2.y);
      } else {
        v0 = make_float4(0,0,0,0); v1 = v0;
      }
      *(float4*)&Abuf[r_][c_]     = v0;
      *(float4*)&Abuf[r_][c_ + 4] = v1;
    }
    __syncthreads();
    short8x aHi, aLo;
    split8(&Abuf[w*16 + m][q*8], aHi, aLo);
#pragma unroll
    for (int tl = 0; tl < 16; tl++) {
      size_t off = (size_t)((ks*16 + tl)*2) * 512 + (size_t)lane*8;
      short8x bh = *(const short8x*)(wB + off);
      short8x bl = *(const short8x*)(wB + off + 512);
      acc[tl] = __builtin_amdgcn_mfma_f32_16x16x32_bf16(aHi, bl, acc[tl], 0, 0, 0);
      acc[tl] = __builtin_amdgcn_mfma_f32_16x16x32_bf16(aLo, bh, acc[tl], 0, 0, 0);
      acc[tl] = __builtin_amdgcn_mfma_f32_16x16x32_bf16(aHi, bh, acc[tl], 0, 0, 0);
    }
  }
  float p0[4] = {0,0,0,0}, p1[4] = {0,0,0,0};
#pragma unroll
  for (int tl = 0; tl < 16; tl++) {
    int col = tl*16 + m;
    float ba = b_a1[col];
    float2 w2 = *(const float2*)&W_a2[col*2];
#pragma unroll
    for (int i = 0; i < 4; i++) {
      float hv = fmaxf(acc[tl][i] + ba, 0.f);
      p0[i] += hv * w2.x;
      p1[i] += hv * w2.y;
    }
  }
#pragma unroll
  for (int off = 1; off < 16; off <<= 1) {
#pragma unroll
    for (int i = 0; i < 4; i++) {
      p0[i] += __shfl_xor(p0[i], off);
      p1[i] += __shfl_xor(p1[i], off);
    }
  }
  if (m == 0) {
    float ba0 = b_a2[0], ba1 = b_a2[1];
    const float hd = 0.5f * DT_ * DT_;
#pragma unroll
    for (int i = 0; i < 4; i++) {
      int n = n0 + w*16 + q*4 + i;
      float ux = tanhf_fast(p0[i] + ba0);
      float uy = tanhf_fast(p1[i] + ba1);
      float4 pv = *(const float4*)&prev[n*4];
      float4 ps = *(const float4*)&prev_st[n*4];
      float4 npv, nps;
      npv.x = pv.x + pv.z*DT_ + ux*hd;
      npv.y = pv.y + pv.w*DT_ + uy*hd;
      npv.z = pv.z + ux*DT_;
      npv.w = pv.w + uy*DT_;
      nps.x = ps.x + ps.z*DT_ + ux*hd;
      nps.y = ps.y + ps.w*DT_ + uy*hd;
      nps.z = ps.z + ux*DT_;
      nps.w = ps.w + uy*DT_;
      *(float4*)&prev[n*4] = npv;
      *(float4*)&prev_st[n*4] = nps;
      *(float4*)&outS[(size_t)n*4] = npv;
      outU[n*2]     = ux;
      outU[n*2 + 1] = uy;
    }
  }
}

// ---------------------------------------------------------------- LSTM h0/c0 + prev copies
__global__ __launch_bounds__(256) void k_init_hc(
    const float* __restrict__ x_last, const float* __restrict__ x_st_last,
    const float* __restrict__ W_h0, const float* __restrict__ b_h0,
    const float* __restrict__ W_c0, const float* __restrict__ b_c0,
    float* __restrict__ h, float* __restrict__ c,
    float* __restrict__ prev, float* __restrict__ prev_st)
{
  const int n = blockIdx.x;
  const int j = threadIdx.x;
  float x0 = x_st_last[n*4], x1 = x_st_last[n*4+1], x2 = x_st_last[n*4+2], x3 = x_st_last[n*4+3];
  h[(size_t)n*256 + j] = b_h0[j] + x0*W_h0[j] + x1*W_h0[256+j] + x2*W_h0[512+j] + x3*W_h0[768+j];
  c[(size_t)n*256 + j] = b_c0[j] + x0*W_c0[j] + x1*W_c0[256+j] + x2*W_c0[512+j] + x3*W_c0[768+j];
  if (j < 4) prev[n*4 + j] = x_last[n*4 + j];
  else if (j < 8) prev_st[n*4 + (j-4)] = x_st_last[n*4 + (j-4)];
}

// ---------------------------------------------------------------- fused edge-MLP(MFMA) + in-register attention
// wave = node; lane = q*16+m. enc stays in MFMA C-layout registers:
// lane (q,m) holds enc[edge=q*4+i][chan=nt*16+m], i=0..3, nt=0..7.
__global__ __launch_bounds__(256, 3) void k_edge_attn(
    const float* __restrict__ prev, const float* __restrict__ prev_st,
    const float* __restrict__ x_st_last,
    const float* __restrict__ szf, const float* __restrict__ rad,
    const int* __restrict__ nobs, const int* __restrict__ e1, const int* __restrict__ e2,
    const float* __restrict__ W_e1, const float* __restrict__ b_e1,
    const unsigned short* __restrict__ wsB, const float* __restrict__ b_e2,
    const float* __restrict__ wattT, const float* __restrict__ W_att2,
    const float* __restrict__ v_att,
    const float* __restrict__ des_p, const float* __restrict__ des_t,
    const float* __restrict__ des_n,
    float* __restrict__ relg, float* __restrict__ nwp, float* __restrict__ nwp2,
    float* __restrict__ ctx, float* __restrict__ ss_t, float* __restrict__ cc)
{
  // LDS (floats): feats[4][16][8] @0 (512) | flags[4][16] @512 | relv[4][4] @576
  //               watt1T[16][128] @592 (2048) | watt2[4][16] @2640 | vatt[16] @2704 | red[8] @2720
  __shared__ __align__(16) float smem[2728];
  float* sm_feats = smem;
  float* sm_flags = smem + 512;
  float* sm_relv  = smem + 576;
  float* sm_w1T   = smem + 592;
  float* sm_watt2 = smem + 2640;
  float* sm_vatt  = smem + 2704;
  float* sm_red   = smem + 2720;

  const int n0  = blockIdx.x * 4;
  const int tid = threadIdx.x;
  const int lane = tid & 63;
  const int g    = tid >> 6;
  const int q = lane >> 4, m = lane & 15;

  // ---- P0: stage small weights + feats/flags/ccost + rel/terr
  for (int i = tid; i < 2048; i += 256) sm_w1T[i] = wattT[i];
  if (tid >= 176 && tid < 192) sm_vatt[tid - 176] = v_att[tid - 176];
  if (tid >= 192) sm_watt2[tid - 192] = W_att2[tid - 192];

  if (tid < 64) {
    float v = 0.f;
    if (tid < 60) {
      int gg = tid / 15, k = tid % 15;
      int idx = nobs[(n0 + gg) * 15 + k];
      float f[8] = {0,0,0,0,0,0,0,0};
      float fl = 0.f;
      if (idx > 0) {
        int e = idx - 1;
        int i1 = e1[e], i2 = e2[e];
#pragma unroll
        for (int d = 0; d < 4; d++) f[d] = prev[i2*4 + d] - prev[i1*4 + d];
        float4 sz = *(const float4*)&szf[(size_t)e*4];
        f[4] = sz.x; f[5] = sz.y; f[6] = sz.z; f[7] = sz.w;
        fl = 1.f;
        float dist = sqrtf(f[0]*f[0] + f[1]*f[1]);
        v = fmaxf(rad[e] - dist, 0.f);
      }
#pragma unroll
      for (int d = 0; d < 8; d++) sm_feats[(gg*16 + k)*8 + d] = f[d];
      sm_flags[gg*16 + k] = fl;
    } else {
      int gg = tid - 60;
#pragma unroll
      for (int d = 0; d < 8; d++) sm_feats[(gg*16 + 15)*8 + d] = 0.f;
      sm_flags[gg*16 + 15] = 0.f;
    }
#pragma unroll
    for (int off = 32; off; off >>= 1) v += __shfl_down(v, off);
    if (tid == 0) atomicAdd(cc, v);
  } else if (tid < 68) {
    int gg = tid - 64;
    int n = n0 + gg;
    float4 ps = *(const float4*)&prev_st[n*4];
    float r0, r1, r2, r3;
    if (des_p) {
      float4 xs = *(const float4*)&x_st_last[n*4];
      r0 = ps.x - xs.x - des_p[n*2];
      r1 = ps.y - xs.y - des_p[n*2 + 1];
      r2 = ps.z - xs.z;
      r3 = ps.w - xs.w;
    } else { r0 = ps.x; r1 = ps.y; r2 = ps.z; r3 = ps.w; }
    sm_relv[gg*4+0] = r0; sm_relv[gg*4+1] = r1; sm_relv[gg*4+2] = r2; sm_relv[gg*4+3] = r3;
    *(float4*)&relg[n*4] = make_float4(r0, r1, r2, r3);
    nwp[n*2]      = des_t[n*2]     - ps.x;
    nwp[n*2 + 1]  = des_t[n*2 + 1] - ps.y;
    nwp2[n*2]     = des_n[n*2]     - ps.x;
    nwp2[n*2 + 1] = des_n[n*2 + 1] - ps.y;
    sm_red[gg] = r0*r0 + r1*r1;
  }
  __syncthreads();
  if (tid == 64) atomicAdd(ss_t, sm_red[0] + sm_red[1] + sm_red[2] + sm_red[3]);

  // ---- P1: hidden = relu(feat@W_e1+b_e1) in A-frag layout, split hi/lo
  float f[8];
  {
    const float4 fa = *(const float4*)&sm_feats[(g*16 + m)*8];
    const float4 fb = *(const float4*)&sm_feats[(g*16 + m)*8 + 4];
    f[0]=fa.x; f[1]=fa.y; f[2]=fa.z; f[3]=fa.w; f[4]=fb.x; f[5]=fb.y; f[6]=fb.z; f[7]=fb.w;
  }
  short8x aHi[8], aLo[8];
  const float4* We14 = (const float4*)W_e1;
  const float4* Be14 = (const float4*)b_e1;
#pragma unroll
  for (int ks = 0; ks < 8; ks++) {
    float h[8];
    {
      float4 b0 = Be14[8*ks + 2*q];
      float4 b1 = Be14[8*ks + 2*q + 1];
      h[0]=b0.x; h[1]=b0.y; h[2]=b0.z; h[3]=b0.w; h[4]=b1.x; h[5]=b1.y; h[6]=b1.z; h[7]=b1.w;
    }
#pragma unroll
    for (int d = 0; d < 8; d++) {
      float4 wa = We14[d*64 + ks*8 + 2*q];
      float4 wb = We14[d*64 + ks*8 + 2*q + 1];
      h[0] += f[d]*wa.x; h[1] += f[d]*wa.y; h[2] += f[d]*wa.z; h[3] += f[d]*wa.w;
      h[4] += f[d]*wb.x; h[5] += f[d]*wb.y; h[6] += f[d]*wb.z; h[7] += f[d]*wb.w;
    }
#pragma unroll
    for (int p = 0; p < 8; p++) h[p] = fmaxf(h[p], 0.f);
    split8(h, aHi[ks], aLo[ks]);
  }

  // ---- P2: enc = hidden @ W_e2 (MFMA), kept in registers encR[nt] (float4x over i)
  float4x fl4 = *(const float4x*)&sm_flags[g*16 + q*4];
  float4x encR[8];
#pragma unroll
  for (int nt = 0; nt < 8; nt++) {
    float4x acc = {0.f, 0.f, 0.f, 0.f};
#pragma unroll
    for (int ks = 0; ks < 8; ks++) {
      size_t off = (size_t)((ks*8 + nt)*2) * 512 + (size_t)lane * 8;
      short8x bh = *(const short8x*)(wsB + off);
      short8x bl = *(const short8x*)(wsB + off + 512);
      acc = __builtin_amdgcn_mfma_f32_16x16x32_bf16(aHi[ks], bl, acc, 0, 0, 0);
      acc = __builtin_amdgcn_mfma_f32_16x16x32_bf16(aLo[ks], bh, acc, 0, 0, 0);
      acc = __builtin_amdgcn_mfma_f32_16x16x32_bf16(aHi[ks], bh, acc, 0, 0, 0);
    }
    float b2 = b_e2[nt*16 + m];
#pragma unroll
    for (int i = 0; i < 4; i++) encR[nt][i] = (acc[i] + b2) * fl4[i];
  }

  // ---- P3: score partials part[a] (float4x over i): Σ_nt enc[nt][i] * W1[nt*16+m][a]
  float4x part[16];
#pragma unroll
  for (int a = 0; a < 16; a++) part[a] = (float4x){0.f,0.f,0.f,0.f};
#pragma unroll
  for (int a = 0; a < 16; a++) {
#pragma unroll
    for (int nt = 0; nt < 8; nt++) {
      float wv = sm_w1T[a*128 + nt*16 + m];
      part[a] = part[a] + encR[nt] * wv;
    }
  }

  // ---- P4: halving-exchange over m (bits 8,4,2,1): lane m ends with column a=m
  const bool s8 = (m & 8) != 0, s4b = (m & 4) != 0, s2b = (m & 2) != 0, s1b = (m & 1) != 0;
  float4x c8[8];
#pragma unroll
  for (int a = 0; a < 8; a++) {
    float4x mi, sd, rc;
#pragma unroll
    for (int e = 0; e < 4; e++) {
      mi[e] = s8 ? part[a+8][e] : part[a][e];
      sd[e] = s8 ? part[a][e] : part[a+8][e];
      rc[e] = __shfl_xor(sd[e], 8);
    }
    c8[a] = mi + rc;
  }
  float4x c4[4];
#pragma unroll
  for (int a = 0; a < 4; a++) {
    float4x mi, sd, rc;
#pragma unroll
    for (int e = 0; e < 4; e++) {
      mi[e] = s4b ? c8[a+4][e] : c8[a][e];
      sd[e] = s4b ? c8[a][e] : c8[a+4][e];
      rc[e] = __shfl_xor(sd[e], 4);
    }
    c4[a] = mi + rc;
  }
  float4x c2[2];
#pragma unroll
  for (int a = 0; a < 2; a++) {
    float4x mi, sd, rc;
#pragma unroll
    for (int e = 0; e < 4; e++) {
      mi[e] = s2b ? c4[a+2][e] : c4[a][e];
      sd[e] = s2b ? c4[a][e] : c4[a+2][e];
      rc[e] = __shfl_xor(sd[e], 2);
    }
    c2[a] = mi + rc;
  }
  float4x c1;
  {
    float4x mi, sd, rc;
#pragma unroll
    for (int e = 0; e < 4; e++) {
      mi[e] = s1b ? c2[1][e] : c2[0][e];
      sd[e] = s1b ? c2[0][e] : c2[1][e];
      rc[e] = __shfl_xor(sd[e], 1);
    }
    c1 = mi + rc;
  }

  // ---- P5: tanh*v_att at a=m, butterfly-sum over a, softmax over edges, ctx
  float relw;
  {
    float4 rv = *(const float4*)&sm_relv[g*4];
    relw = rv.x * sm_watt2[m] + rv.y * sm_watt2[16 + m]
         + rv.z * sm_watt2[32 + m] + rv.w * sm_watt2[48 + m];
  }
  float vat = sm_vatt[m];
  float val[4];
#pragma unroll
  for (int i = 0; i < 4; i++) val[i] = tanhf_fast(c1[i] + relw) * vat;
#pragma unroll
  for (int msk = 1; msk < 16; msk <<= 1) {
#pragma unroll
    for (int i = 0; i < 4; i++) val[i] += __shfl_xor(val[i], msk);
  }
  // mask artificial 16th edge, softmax over 16 (pad weight -> exactly 0)
  if (q == 3) val[3] = -3.0e38f;
  float mx = fmaxf(fmaxf(val[0], val[1]), fmaxf(val[2], val[3]));
  mx = fmaxf(mx, __shfl_xor(mx, 16));
  mx = fmaxf(mx, __shfl_xor(mx, 32));
  float4x ev;
  float ssum = 0.f;
#pragma unroll
  for (int i = 0; i < 4; i++) { ev[i] = __expf(val[i] - mx); ssum += ev[i]; }
  ssum += __shfl_xor(ssum, 16);
  ssum += __shfl_xor(ssum, 32);
  float inv = 1.f / ssum;
#pragma unroll
  for (int i = 0; i < 4; i++) ev[i] *= inv;

  float cpart[8];
#pragma unroll
  for (int nt = 0; nt < 8; nt++) {
    float cv = ev[0]*encR[nt][0] + ev[1]*encR[nt][1] + ev[2]*encR[nt][2] + ev[3]*encR[nt][3];
    cv += __shfl_xor(cv, 16);
    cv += __shfl_xor(cv, 32);
    cpart[nt] = cv;
  }
  // lane (q,m) stores chans q*32+m and q*32+16+m (static-index select on q)
  float v0 = (q == 0) ? cpart[0] : (q == 1) ? cpart[2] : (q == 2) ? cpart[4] : cpart[6];
  float v1 = (q == 0) ? cpart[1] : (q == 1) ? cpart[3] : (q == 2) ? cpart[5] : cpart[7];
  size_t cb = (size_t)(n0 + g) * 128 + q*32 + m;
  ctx[cb]      = v0;
  ctx[cb + 16] = v1;
}

// ---------------------------------------------------------------- finalize scalars
__global__ void k_final(const float* __restrict__ ss, float* __restrict__ out) {
  if (threadIdx.x == 0) {
    float t = 0.f;
    for (int i = 0; i < FTS; i++) t += sqrtf(ss[i]);
    out[(size_t)FTS * N_ * 6]     = t / (float)N_;
    out[(size_t)FTS * N_ * 6 + 1] = ss[FTS];
  }
}

// ================================================================ launch
extern "C" void kernel_launch(void* const* d_in, const int* in_sizes, int n_in,
                              void* d_out, int out_size, void* d_ws, size_t ws_size,
                              hipStream_t stream) {
  (void)in_sizes; (void)n_in; (void)out_size; (void)ws_size;
  const float* x_last    = (const float*)d_in[0];
  const float* x_st_last = (const float*)d_in[1];
  const float* hist_enc  = (const float*)d_in[2];
  const float* z         = (const float*)d_in[3];
  const float* node_size = (const float*)d_in[4];
  const float* W_h0 = (const float*)d_in[5];
  const float* b_h0 = (const float*)d_in[6];
  const float* W_c0 = (const float*)d_in[7];
  const float* b_c0 = (const float*)d_in[8];
  const float* W_gh = (const float*)d_in[9];
  const float* b_gh = (const float*)d_in[10];
  const float* W_gih = (const float*)d_in[11];
  const float* W_ghh = (const float*)d_in[12];
  const float* b_gih = (const float*)d_in[13];
  const float* b_ghh = (const float*)d_in[14];
  const float* W_proj = (const float*)d_in[15];
  const float* b_proj = (const float*)d_in[16];
  const float* W_att1 = (const float*)d_in[17];
  const float* W_att2 = (const float*)d_in[18];
  const float* v_att  = (const float*)d_in[19];
  const float* W_lih = (const float*)d_in[20];
  const float* W_lhh = (const float*)d_in[21];
  const float* b_lih = (const float*)d_in[22];
  const float* b_lhh = (const float*)d_in[23];
  const float* W_e1 = (const float*)d_in[24];
  const float* b_e1 = (const float*)d_in[25];
  const float* W_e2 = (const float*)d_in[26];
  const float* b_e2 = (const float*)d_in[27];
  const float* W_a1 = (const float*)d_in[28];
  const float* b_a1 = (const float*)d_in[29];
  const float* W_a2 = (const float*)d_in[30];
  const float* b_a2 = (const float*)d_in[31];
  const int* e1   = (const int*)d_in[32];
  const int* e2   = (const int*)d_in[33];
  const int* nobs = (const int*)d_in[34];
  float* out = (float*)d_out;

  // workspace carve (floats)
  float* wsf     = (float*)d_ws;
  float* prev    = wsf;                     // 32768
  float* prev_st = wsf + 32768;             // 32768
  float* des     = wsf + 65536;             // 196608
  float* ss      = wsf + 262144;            // 16
  float* rad     = wsf + 262160;            // 122880
  float* szf     = wsf + 385040;            // 491520 -> end 876560
  float* baseA   = wsf + 876560;            // union region, 10485760 floats -> end 11362320
  // GRU phase view
  float* gh0 = baseA;
  float* gh1 = baseA + (size_t)N_ * 256;
  float* gi  = baseA + (size_t)2 * N_ * 256;
  // main phase view (aliases GRU-phase buffers, dead by then)
  float* hA   = baseA;
  float* hB   = baseA + (size_t)N_ * 256;
  float* cbuf = baseA + (size_t)2 * N_ * 256;
  float* ctx  = baseA + (size_t)3 * N_ * 256;
  float* rel  = baseA + (size_t)4 * N_ * 256;
  float* nwp  = rel + (size_t)N_ * 4;
  float* nwp2 = nwp + (size_t)N_ * 2;
  // prepped B fragments — after the full union region
  unsigned short* wsBe = (unsigned short*)(wsf + 11362320);  //  64 frags
  unsigned short* wsBg = (unsigned short*)(wsf + 11427856);  // 384 frags
  unsigned short* wsBl = (unsigned short*)(wsf + 11624464);  // 768 frags
  unsigned short* wsBx = (unsigned short*)(wsf + 12017680);  // 576 frags
  unsigned short* wsBa = (unsigned short*)(wsf + 12312592);  // 144 frags -> end 12386320 fl
  float* wattT = wsf + 12386320;                             // 2048 fl -> end 12388368

  k_zero<<<1, 64, 0, stream>>>(ss);
  k_edge_static<<<(E_ + 255) / 256, 256, 0, stream>>>(e1, e2, node_size, rad, szf);
  k_init_des<<<FTS * N_ / 256, 256, 0, stream>>>(b_proj, des);
  k_prep_attT<<<8, 256, 0, stream>>>(W_att1, wattT);

  k_prep<<<16,  256, 0, stream>>>(W_e2,  W_e2,  0, 256, 128,  128,  256, 8,  64,  wsBe);
  k_prep<<<96,  256, 0, stream>>>(W_ghh, W_ghh, 0, 256, 768,  768,  256, 48, 384, wsBg);
  k_prep<<<192, 256, 0, stream>>>(W_lih, W_lhh, 0, 128, 1024, 1024, 384, 64, 768, wsBl);
  k_prep<<<144, 256, 0, stream>>>(W_gh,  W_gih, 1, 256, 256,  768,  264, 64, 576, wsBx);
  k_prep<<<36,  256, 0, stream>>>(W_a1,  W_a1,  0, 272, 256,  256,  272, 16, 144, wsBa);

  // guide GRU phase
  k_xz_mfma<<<dim3(128, 4), 256, 0, stream>>>(hist_enc, z, wsBx, b_gh, b_gih, gh0, gi);
  float* gcur = gh0;
  float* gnxt = gh1;
  for (int t = 0; t < FTS; t++) {
    k_gru_mfma<<<dim3(128, 4), 256, 0, stream>>>(gcur, wsBg, b_ghh, gi, W_proj,
                                                 des + (size_t)t * N_ * 2, gnxt);
    float* tmp = gcur; gcur = gnxt; gnxt = tmp;
  }

  // main rollout
  k_init_hc<<<N_, 256, 0, stream>>>(x_last, x_st_last, W_h0, b_h0, W_c0, b_c0,
                                    hA, cbuf, prev, prev_st);
  float* hcur = hA;
  float* hnxt = hB;
  for (int t = 0; t < FTS; t++) {
    const float* des_t = des + (size_t)t * N_ * 2;
    const float* des_n = des + (size_t)((t + 1 < FTS) ? t + 1 : FTS - 1) * N_ * 2;
    const float* des_p = (t > 0) ? des + (size_t)(t - 1) * N_ * 2 : nullptr;
    k_edge_attn<<<N_ / 4, 256, 0, stream>>>(prev, prev_st, x_st_last, szf, rad,
                                            nobs, e1, e2, W_e1, b_e1, wsBe, b_e2,
                                            wattT, W_att2, v_att,
                                            des_p, des_t, des_n,
                                            rel, nwp, nwp2, ctx, ss + t, ss + 12);
    k_lstm_mfma<<<dim3(128, 4), 256, 0, stream>>>(ctx, hcur, wsBl, b_lih, b_lhh,
                                                  cbuf, hnxt);
    k_action_mfma<<<128, 256, 0, stream>>>(hnxt, z, rel, nwp, nwp2,
                                           wsBa, b_a1, W_a2, b_a2,
                                           prev, prev_st,
                                           out + (size_t)t * N_ * 4,
                                           out + (size_t)FTS * N_ * 4 + (size_t)t * N_ * 2);
    float* tmp = hcur; hcur = hnxt; hnxt = tmp;
  }
  k_final<<<1, 64, 0, stream>>>(ss, out);
}

// Round 5
// 2559.317 us; speedup vs baseline: 1.9433x; 1.2072x over previous
//
#include <hip/hip_runtime.h>

#define DEVI __device__ __forceinline__

constexpr int N_  = 8192;
constexpr int K_  = 15;
constexpr int E_  = N_ * K_;     // 122880
constexpr int FTS = 12;
constexpr float DT_ = 0.25f;

typedef __attribute__((ext_vector_type(8))) short short8x;
typedef __attribute__((ext_vector_type(4))) float float4x;

union U8 { unsigned int u[4]; short8x v; };

DEVI float sigf(float x) { return 1.0f / (1.0f + __expf(-x)); }
DEVI float tanhf_fast(float x) { float e = __expf(2.f * x); return 1.f - 2.f / (e + 1.f); }
DEVI unsigned int f2u(float x) { union { float f; unsigned int u; } c; c.f = x; return c.u; }
DEVI float u2f(unsigned int x) { union { unsigned int u; float f; } c; c.u = x; return c.f; }

DEVI void split8(const float* __restrict__ s, short8x& hi8, short8x& lo8) {
  U8 ph, pl;
#pragma unroll
  for (int p = 0; p < 4; p++) {
    float a0 = s[2*p], a1 = s[2*p+1];
    unsigned int u0 = f2u(a0), u1 = f2u(a1);
    unsigned int h0 = u0 & 0xFFFF0000u, h1 = u1 & 0xFFFF0000u;
    ph.u[p] = (u0 >> 16) | h1;
    float l0 = a0 - u2f(h0), l1 = a1 - u2f(h1);
    pl.u[p] = (f2u(l0) >> 16) | (f2u(l1) & 0xFFFF0000u);
  }
  hi8 = ph.v; lo8 = pl.v;
}

// ---------------------------------------------------------------- zero accum
__global__ void k_zero(float* ss) {
  if (threadIdx.x < 13) ss[threadIdx.x] = 0.f;
}

// ---------------------------------------------------------------- init des to b_proj
__global__ __launch_bounds__(256) void k_init_des(const float* __restrict__ b_proj,
                                                  float* __restrict__ des) {
  int i = blockIdx.x * 256 + threadIdx.x;
  des[i*2]     = b_proj[0];
  des[i*2 + 1] = b_proj[1];
}

// ---------------------------------------------------------------- edge static
__global__ __launch_bounds__(256) void k_edge_static(
    const int* __restrict__ e1, const int* __restrict__ e2,
    const float* __restrict__ nsize, float* __restrict__ rad, float* __restrict__ szf)
{
  int e = blockIdx.x * 256 + threadIdx.x;
  if (e >= E_) return;
  int i1 = e1[e], i2 = e2[e];
  float s1x = nsize[i1*2+0], s1y = nsize[i1*2+1];
  float s2x = nsize[i2*2+0], s2y = nsize[i2*2+1];
  rad[e] = 0.5f * (sqrtf(s1x*s1x + s1y*s1y) + sqrtf(s2x*s2x + s2y*s2y));
  *(float4*)&szf[e*4] = make_float4(s1x, s1y, s2x, s2y);
}

// ---------------------------------------------------------------- transpose W_att1 -> [a][chan]
__global__ __launch_bounds__(256) void k_prep_attT(const float* __restrict__ W_att1,
                                                   float* __restrict__ wT) {
  int i = blockIdx.x * 256 + threadIdx.x;
  int chan = i >> 4, a = i & 15;
  wT[a * 128 + chan] = W_att1[i];
}

// ---------------------------------------------------------------- generic split-bf16 B-fragment prep
__global__ __launch_bounds__(256) void k_prep(
    const float* __restrict__ WA, const float* __restrict__ WB,
    int mode, int split, int wA, int wB, int Ktot, int NT, int nfrag,
    unsigned short* __restrict__ out)
{
  int t = blockIdx.x * 256 + threadIdx.x;
  int fid = t >> 6, L = t & 63;
  if (fid >= nfrag) return;
  int ks = fid / NT, nt = fid % NT;
  int k0 = ks * 32 + (L >> 4) * 8;
  int n  = nt * 16 + (L & 15);
  unsigned int hi[4], lo[4];
#pragma unroll
  for (int p = 0; p < 4; p++) {
    float w0 = 0.f, w1 = 0.f;
    int ka = k0 + 2*p, kb = ka + 1;
    if (mode == 0) {
      if (ka < Ktot) w0 = (ka < split) ? WA[(size_t)ka*wA + n] : WB[(size_t)(ka-split)*wB + n];
      if (kb < Ktot) w1 = (kb < split) ? WA[(size_t)kb*wA + n] : WB[(size_t)(kb-split)*wB + n];
    } else {
      if (ka < Ktot) w0 = (n < split) ? WA[(size_t)ka*wA + n] : WB[(size_t)ka*wB + (n-split)];
      if (kb < Ktot) w1 = (n < split) ? WA[(size_t)kb*wA + n] : WB[(size_t)kb*wB + (n-split)];
    }
    unsigned int u0 = f2u(w0), u1 = f2u(w1);
    unsigned int h0 = u0 & 0xFFFF0000u, h1 = u1 & 0xFFFF0000u;
    hi[p] = (u0 >> 16) | h1;
    float l0 = w0 - u2f(h0), l1 = w1 - u2f(h1);
    lo[p] = (f2u(l0) >> 16) | (f2u(l1) & 0xFFFF0000u);
  }
  size_t base = (size_t)(fid * 2) * 512 + (size_t)L * 8;
  *(uint4*)(out + base)       = make_uint4(hi[0], hi[1], hi[2], hi[3]);
  *(uint4*)(out + base + 512) = make_uint4(lo[0], lo[1], lo[2], lo[3]);
}

// ---------------------------------------------------------------- xz GEMM (once)
__global__ __launch_bounds__(256) void k_xz_mfma(
    const float* __restrict__ hist, const float* __restrict__ z,
    const unsigned short* __restrict__ wB,
    const float* __restrict__ b_gh, const float* __restrict__ b_gih,
    float* __restrict__ gh0, float* __restrict__ gi)
{
  __shared__ __align__(16) float Abuf[64][36];
  const int tid = threadIdx.x;
  const int w = tid >> 6, lane = tid & 63;
  const int m = lane & 15, q = lane >> 4;
  const int n0 = blockIdx.x * 64;
  const int r_ = tid >> 2, c_ = (tid & 3) * 8;
  float4x acc[16];
#pragma unroll
  for (int tl = 0; tl < 16; tl++) acc[tl] = (float4x){0.f,0.f,0.f,0.f};

  for (int ks = 0; ks < 9; ks++) {
    __syncthreads();
    {
      int kk = ks*32 + c_;
      int n = n0 + r_;
      float4 v0, v1;
      if (kk < 256) {
        v0 = *(const float4*)&hist[(size_t)n*256 + kk];
        v1 = *(const float4*)&hist[(size_t)n*256 + kk + 4];
      } else if (kk == 256) {
        v0 = *(const float4*)&z[n*8];
        v1 = *(const float4*)&z[n*8 + 4];
      } else {
        v0 = make_float4(0,0,0,0); v1 = v0;
      }
      *(float4*)&Abuf[r_][c_]     = v0;
      *(float4*)&Abuf[r_][c_ + 4] = v1;
    }
    __syncthreads();
    short8x aHi, aLo;
    split8(&Abuf[w*16 + m][q*8], aHi, aLo);
#pragma unroll
    for (int tl = 0; tl < 16; tl++) {
      int nt = blockIdx.y*16 + tl;
      size_t off = (size_t)((ks*64 + nt)*2) * 512 + (size_t)lane*8;
      short8x bh = *(const short8x*)(wB + off);
      short8x bl = *(const short8x*)(wB + off + 512);
      acc[tl] = __builtin_amdgcn_mfma_f32_16x16x32_bf16(aHi, bl, acc[tl], 0, 0, 0);
      acc[tl] = __builtin_amdgcn_mfma_f32_16x16x32_bf16(aLo, bh, acc[tl], 0, 0, 0);
      acc[tl] = __builtin_amdgcn_mfma_f32_16x16x32_bf16(aHi, bh, acc[tl], 0, 0, 0);
    }
  }
#pragma unroll
  for (int tl = 0; tl < 16; tl++) {
    int col = (blockIdx.y*16 + tl)*16 + m;
    float bias = (col < 256) ? b_gh[col] : b_gih[col - 256];
#pragma unroll
    for (int i = 0; i < 4; i++) {
      int n = n0 + w*16 + q*4 + i;
      float v = acc[tl][i] + bias;
      if (col < 256) gh0[(size_t)n*256 + col] = v;
      else           gi[(size_t)n*768 + col - 256] = v;
    }
  }
}

// ---------------------------------------------------------------- GRU core (shared by standalone + fused)
DEVI void gru_core(float (*Abuf)[36], int tid, int n0, int j0,
                   const float* __restrict__ h_in, const unsigned short* __restrict__ wB,
                   const float* __restrict__ b_hh, const float* __restrict__ gi,
                   const float* __restrict__ W_proj, float* __restrict__ des_t,
                   float* __restrict__ h_out)
{
  const int w = tid >> 6, lane = tid & 63;
  const int m = lane & 15, q = lane >> 4;
  const int r_ = tid >> 2, c_ = (tid & 3) * 8;
  float4x acc[12];
#pragma unroll
  for (int tl = 0; tl < 12; tl++) acc[tl] = (float4x){0.f,0.f,0.f,0.f};

  for (int ks = 0; ks < 8; ks++) {
    __syncthreads();
    {
      int kk = ks*32 + c_;
      int n = n0 + r_;
      *(float4*)&Abuf[r_][c_]     = *(const float4*)&h_in[(size_t)n*256 + kk];
      *(float4*)&Abuf[r_][c_ + 4] = *(const float4*)&h_in[(size_t)n*256 + kk + 4];
    }
    __syncthreads();
    short8x aHi, aLo;
    split8(&Abuf[w*16 + m][q*8], aHi, aLo);
#pragma unroll
    for (int tl = 0; tl < 12; tl++) {
      int g = tl >> 2, jt = tl & 3;
      int nt = g*16 + (j0 >> 4) + jt;
      size_t off = (size_t)((ks*48 + nt)*2) * 512 + (size_t)lane*8;
      short8x bh = *(const short8x*)(wB + off);
      short8x bl = *(const short8x*)(wB + off + 512);
      acc[tl] = __builtin_amdgcn_mfma_f32_16x16x32_bf16(aHi, bl, acc[tl], 0, 0, 0);
      acc[tl] = __builtin_amdgcn_mfma_f32_16x16x32_bf16(aLo, bh, acc[tl], 0, 0, 0);
      acc[tl] = __builtin_amdgcn_mfma_f32_16x16x32_bf16(aHi, bh, acc[tl], 0, 0, 0);
    }
  }
  float pd0[4] = {0,0,0,0}, pd1[4] = {0,0,0,0};
#pragma unroll
  for (int jt = 0; jt < 4; jt++) {
    int j = j0 + jt*16 + m;
    float br = b_hh[j], bz = b_hh[256 + j], bn = b_hh[512 + j];
    float wp0 = W_proj[j*2], wp1 = W_proj[j*2 + 1];
#pragma unroll
    for (int i = 0; i < 4; i++) {
      int n = n0 + w*16 + q*4 + i;
      float ir  = gi[(size_t)n*768 + j];
      float iz  = gi[(size_t)n*768 + 256 + j];
      float inn = gi[(size_t)n*768 + 512 + j];
      float hold = h_in[(size_t)n*256 + j];
      float r = sigf(ir + acc[0*4 + jt][i] + br);
      float u = sigf(iz + acc[1*4 + jt][i] + bz);
      float nh = (1.f - u) * tanhf_fast(inn + r * (acc[2*4 + jt][i] + bn)) + u * hold;
      h_out[(size_t)n*256 + j] = nh;
      pd0[i] += nh * wp0;
      pd1[i] += nh * wp1;
    }
  }
#pragma unroll
  for (int off = 1; off < 16; off <<= 1) {
#pragma unroll
    for (int i = 0; i < 4; i++) {
      pd0[i] += __shfl_xor(pd0[i], off);
      pd1[i] += __shfl_xor(pd1[i], off);
    }
  }
  if (m == 0) {
#pragma unroll
    for (int i = 0; i < 4; i++) {
      int n = n0 + w*16 + q*4 + i;
      atomicAdd(&des_t[n*2],     pd0[i]);
      atomicAdd(&des_t[n*2 + 1], pd1[i]);
    }
  }
}

// ---------------------------------------------------------------- standalone GRU step
__global__ __launch_bounds__(256) void k_gru_mfma(
    const float* __restrict__ h_in, const unsigned short* __restrict__ wB,
    const float* __restrict__ b_hh, const float* __restrict__ gi,
    const float* __restrict__ W_proj, float* __restrict__ des_t,
    float* __restrict__ h_out)
{
  __shared__ __align__(16) float Abuf[64][36];
  gru_core(Abuf, threadIdx.x, blockIdx.x * 64, blockIdx.y * 64,
           h_in, wB, b_hh, gi, W_proj, des_t, h_out);
}

// ---------------------------------------------------------------- LSTM cell (MFMA)
__global__ __launch_bounds__(256) void k_lstm_mfma(
    const float* __restrict__ ctxg, const float* __restrict__ h_in,
    const unsigned short* __restrict__ wB,
    const float* __restrict__ b_ih, const float* __restrict__ b_hh,
    float* __restrict__ c_st, float* __restrict__ h_out)
{
  __shared__ __align__(16) float Abuf[64][36];
  const int tid = threadIdx.x;
  const int w = tid >> 6, lane = tid & 63;
  const int m = lane & 15, q = lane >> 4;
  const int n0 = blockIdx.x * 64;
  const int j0 = blockIdx.y * 64;
  const int r_ = tid >> 2, c_ = (tid & 3) * 8;
  float4x acc[16];
#pragma unroll
  for (int tl = 0; tl < 16; tl++) acc[tl] = (float4x){0.f,0.f,0.f,0.f};

  for (int ks = 0; ks < 12; ks++) {
    __syncthreads();
    {
      int kk = ks*32 + c_;
      int n = n0 + r_;
      float4 v0, v1;
      if (kk < 128) {
        v0 = *(const float4*)&ctxg[(size_t)n*128 + kk];
        v1 = *(const float4*)&ctxg[(size_t)n*128 + kk + 4];
      } else {
        v0 = *(const float4*)&h_in[(size_t)n*256 + kk - 128];
        v1 = *(const float4*)&h_in[(size_t)n*256 + kk - 124];
      }
      *(float4*)&Abuf[r_][c_]     = v0;
      *(float4*)&Abuf[r_][c_ + 4] = v1;
    }
    __syncthreads();
    short8x aHi, aLo;
    split8(&Abuf[w*16 + m][q*8], aHi, aLo);
#pragma unroll
    for (int tl = 0; tl < 16; tl++) {
      int g = tl >> 2, jt = tl & 3;
      int nt = g*16 + (j0 >> 4) + jt;
      size_t off = (size_t)((ks*64 + nt)*2) * 512 + (size_t)lane*8;
      short8x bh = *(const short8x*)(wB + off);
      short8x bl = *(const short8x*)(wB + off + 512);
      acc[tl] = __builtin_amdgcn_mfma_f32_16x16x32_bf16(aHi, bl, acc[tl], 0, 0, 0);
      acc[tl] = __builtin_amdgcn_mfma_f32_16x16x32_bf16(aLo, bh, acc[tl], 0, 0, 0);
      acc[tl] = __builtin_amdgcn_mfma_f32_16x16x32_bf16(aHi, bh, acc[tl], 0, 0, 0);
    }
  }
#pragma unroll
  for (int jt = 0; jt < 4; jt++) {
    int j = j0 + jt*16 + m;
    float bi = b_ih[j]       + b_hh[j];
    float bf = b_ih[256 + j] + b_hh[256 + j];
    float bg = b_ih[512 + j] + b_hh[512 + j];
    float bo = b_ih[768 + j] + b_hh[768 + j];
#pragma unroll
    for (int i = 0; i < 4; i++) {
      int n = n0 + w*16 + q*4 + i;
      float g_i = sigf(acc[0*4 + jt][i] + bi);
      float g_f = sigf(acc[1*4 + jt][i] + bf);
      float g_g = tanhf_fast(acc[2*4 + jt][i] + bg);
      float g_o = sigf(acc[3*4 + jt][i] + bo);
      float cv = g_f * c_st[(size_t)n*256 + j] + g_i * g_g;
      c_st[(size_t)n*256 + j] = cv;
      h_out[(size_t)n*256 + j] = g_o * tanhf_fast(cv);
    }
  }
}

// ---------------------------------------------------------------- action MLP: 32 nodes/block, hidden split across wave pairs
__global__ __launch_bounds__(256) void k_action_mfma(
    const float* __restrict__ h, const float* __restrict__ z,
    const float* __restrict__ rel, const float* __restrict__ nwp, const float* __restrict__ nwp2,
    const unsigned short* __restrict__ wB, const float* __restrict__ b_a1,
    const float* __restrict__ W_a2, const float* __restrict__ b_a2,
    float* __restrict__ prev, float* __restrict__ prev_st,
    float* __restrict__ outS, float* __restrict__ outU)
{
  __shared__ __align__(16) float Abuf[32][36];
  __shared__ float sm_p[2][16][2];
  const int tid = threadIdx.x;
  const int w = tid >> 6, lane = tid & 63;
  const int m = lane & 15, q = lane >> 4;
  const int ng = w >> 1, hh = w & 1;
  const int n0 = blockIdx.x * 32;
  const int r_ = tid >> 3, c_ = (tid & 7) * 4;
  float4x acc[8];
#pragma unroll
  for (int j = 0; j < 8; j++) acc[j] = (float4x){0.f,0.f,0.f,0.f};

  for (int ks = 0; ks < 9; ks++) {
    __syncthreads();
    {
      int kk = ks*32 + c_;
      int n = n0 + r_;
      float4 v;
      if (kk < 256)      v = *(const float4*)&h[(size_t)n*256 + kk];
      else if (kk == 256) v = *(const float4*)&z[n*8];
      else if (kk == 260) v = *(const float4*)&z[n*8 + 4];
      else if (kk == 264) v = *(const float4*)&rel[n*4];
      else if (kk == 268) {
        float2 w1 = *(const float2*)&nwp[n*2];
        float2 w2 = *(const float2*)&nwp2[n*2];
        v = make_float4(w1.x, w1.y, w2.x, w2.y);
      } else v = make_float4(0,0,0,0);
      *(float4*)&Abuf[r_][c_] = v;
    }
    __syncthreads();
    short8x aHi, aLo;
    split8(&Abuf[ng*16 + m][q*8], aHi, aLo);
#pragma unroll
    for (int j = 0; j < 8; j++) {
      int tl = hh*8 + j;
      size_t off = (size_t)((ks*16 + tl)*2) * 512 + (size_t)lane*8;
      short8x bh = *(const short8x*)(wB + off);
      short8x bl = *(const short8x*)(wB + off + 512);
      acc[j] = __builtin_amdgcn_mfma_f32_16x16x32_bf16(aHi, bl, acc[j], 0, 0, 0);
      acc[j] = __builtin_amdgcn_mfma_f32_16x16x32_bf16(aLo, bh, acc[j], 0, 0, 0);
      acc[j] = __builtin_amdgcn_mfma_f32_16x16x32_bf16(aHi, bh, acc[j], 0, 0, 0);
    }
  }
  float p0[4] = {0,0,0,0}, p1[4] = {0,0,0,0};
#pragma unroll
  for (int j = 0; j < 8; j++) {
    int col = (hh*8 + j)*16 + m;
    float ba = b_a1[col];
    float2 w2 = *(const float2*)&W_a2[col*2];
#pragma unroll
    for (int i = 0; i < 4; i++) {
      float hv = fmaxf(acc[j][i] + ba, 0.f);
      p0[i] += hv * w2.x;
      p1[i] += hv * w2.y;
    }
  }
#pragma unroll
  for (int off = 1; off < 16; off <<= 1) {
#pragma unroll
    for (int i = 0; i < 4; i++) {
      p0[i] += __shfl_xor(p0[i], off);
      p1[i] += __shfl_xor(p1[i], off);
    }
  }
  if (hh == 1 && m == 0) {
#pragma unroll
    for (int i = 0; i < 4; i++) {
      sm_p[ng][q*4 + i][0] = p0[i];
      sm_p[ng][q*4 + i][1] = p1[i];
    }
  }
  __syncthreads();
  if (hh == 0 && m == 0) {
    float ba0 = b_a2[0], ba1 = b_a2[1];
    const float hd = 0.5f * DT_ * DT_;
#pragma unroll
    for (int i = 0; i < 4; i++) {
      int n = n0 + ng*16 + q*4 + i;
      float ux = tanhf_fast(p0[i] + sm_p[ng][q*4 + i][0] + ba0);
      float uy = tanhf_fast(p1[i] + sm_p[ng][q*4 + i][1] + ba1);
      float4 pv = *(const float4*)&prev[n*4];
      float4 ps = *(const float4*)&prev_st[n*4];
      float4 npv, nps;
      npv.x = pv.x + pv.z*DT_ + ux*hd;
      npv.y = pv.y + pv.w*DT_ + uy*hd;
      npv.z = pv.z + ux*DT_;
      npv.w = pv.w + uy*DT_;
      nps.x = ps.x + ps.z*DT_ + ux*hd;
      nps.y = ps.y + ps.w*DT_ + uy*hd;
      nps.z = ps.z + ux*DT_;
      nps.w = ps.w + uy*DT_;
      *(float4*)&prev[n*4] = npv;
      *(float4*)&prev_st[n*4] = nps;
      *(float4*)&outS[(size_t)n*4] = npv;
      outU[n*2]     = ux;
      outU[n*2 + 1] = uy;
    }
  }
}

// ---------------------------------------------------------------- LSTM h0/c0 + prev copies
__global__ __launch_bounds__(256) void k_init_hc(
    const float* __restrict__ x_last, const float* __restrict__ x_st_last,
    const float* __restrict__ W_h0, const float* __restrict__ b_h0,
    const float* __restrict__ W_c0, const float* __restrict__ b_c0,
    float* __restrict__ h, float* __restrict__ c,
    float* __restrict__ prev, float* __restrict__ prev_st)
{
  const int n = blockIdx.x;
  const int j = threadIdx.x;
  float x0 = x_st_last[n*4], x1 = x_st_last[n*4+1], x2 = x_st_last[n*4+2], x3 = x_st_last[n*4+3];
  h[(size_t)n*256 + j] = b_h0[j] + x0*W_h0[j] + x1*W_h0[256+j] + x2*W_h0[512+j] + x3*W_h0[768+j];
  c[(size_t)n*256 + j] = b_c0[j] + x0*W_c0[j] + x1*W_c0[256+j] + x2*W_c0[512+j] + x3*W_c0[768+j];
  if (j < 4) prev[n*4 + j] = x_last[n*4 + j];
  else if (j < 8) prev_st[n*4 + (j-4)] = x_st_last[n*4 + (j-4)];
}

// ---------------------------------------------------------------- FUSED: edge-MLP+attention (blocks 0..2047) | GRU step (blocks 2048..2559)
__global__ __launch_bounds__(256, 4) void k_edge_gru(
    const float* __restrict__ prev, const float* __restrict__ prev_st,
    const float* __restrict__ x_st_last,
    const float* __restrict__ szf, const float* __restrict__ rad,
    const int* __restrict__ nobs, const int* __restrict__ e1, const int* __restrict__ e2,
    const float* __restrict__ W_e1, const float* __restrict__ b_e1,
    const unsigned short* __restrict__ wsB, const float* __restrict__ b_e2,
    const float* __restrict__ wattT, const float* __restrict__ W_att2,
    const float* __restrict__ v_att,
    const float* __restrict__ des_p, const float* __restrict__ des_t,
    const float* __restrict__ des_n,
    float* __restrict__ relg, float* __restrict__ nwp, float* __restrict__ nwp2,
    float* __restrict__ ctx, float* __restrict__ ss_t, float* __restrict__ cc,
    const float* __restrict__ g_hin, const unsigned short* __restrict__ wBg,
    const float* __restrict__ b_ghh, const float* __restrict__ gi,
    const float* __restrict__ W_proj, float* __restrict__ des_g,
    float* __restrict__ g_hout, int gru_on)
{
  // LDS: stage[4096] | feats[512]@4096 | flags[64]@4608 | relv[16]@4672
  //      w1T[2048]@4688 | watt2[64]@6736 | vatt[16]@6800 | red[8]@6816  -> 6824 floats
  __shared__ __align__(16) float smem[6824];

  const int tid = threadIdx.x;

  if (blockIdx.x >= 2048) {
    if (!gru_on) return;
    int b = blockIdx.x - 2048;
    gru_core((float(*)[36])smem, tid, (b & 127) * 64, (b >> 7) * 64,
             g_hin, wBg, b_ghh, gi, W_proj, des_g, g_hout);
    return;
  }

  float* sm_stage = smem;
  float* sm_feats = smem + 4096;
  float* sm_flags = smem + 4608;
  float* sm_relv  = smem + 4672;
  float* sm_w1T   = smem + 4688;
  float* sm_watt2 = smem + 6736;
  float* sm_vatt  = smem + 6800;
  float* sm_red   = smem + 6816;

  const int n0  = blockIdx.x * 4;
  const int lane = tid & 63;
  const int g    = tid >> 6;
  const int q = lane >> 4, m = lane & 15;

  // ---- P0
  for (int i = tid; i < 2048; i += 256) sm_w1T[i] = wattT[i];
  if (tid >= 176 && tid < 192) sm_vatt[tid - 176] = v_att[tid - 176];
  if (tid >= 192) sm_watt2[tid - 192] = W_att2[tid - 192];

  if (tid < 64) {
    float v = 0.f;
    if (tid < 60) {
      int gg = tid / 15, k = tid % 15;
      int idx = nobs[(n0 + gg) * 15 + k];
      float f[8] = {0,0,0,0,0,0,0,0};
      float fl = 0.f;
      if (idx > 0) {
        int e = idx - 1;
        int i1 = e1[e], i2 = e2[e];
#pragma unroll
        for (int d = 0; d < 4; d++) f[d] = prev[i2*4 + d] - prev[i1*4 + d];
        float4 sz = *(const float4*)&szf[(size_t)e*4];
        f[4] = sz.x; f[5] = sz.y; f[6] = sz.z; f[7] = sz.w;
        fl = 1.f;
        float dist = sqrtf(f[0]*f[0] + f[1]*f[1]);
        v = fmaxf(rad[e] - dist, 0.f);
      }
#pragma unroll
      for (int d = 0; d < 8; d++) sm_feats[(gg*16 + k)*8 + d] = f[d];
      sm_flags[gg*16 + k] = fl;
    } else {
      int gg = tid - 60;
#pragma unroll
      for (int d = 0; d < 8; d++) sm_feats[(gg*16 + 15)*8 + d] = 0.f;
      sm_flags[gg*16 + 15] = 0.f;
    }
#pragma unroll
    for (int off = 32; off; off >>= 1) v += __shfl_down(v, off);
    if (tid == 0) atomicAdd(cc, v);
  } else if (tid < 68) {
    int gg = tid - 64;
    int n = n0 + gg;
    float4 ps = *(const float4*)&prev_st[n*4];
    float r0, r1, r2, r3;
    if (des_p) {
      float4 xs = *(const float4*)&x_st_last[n*4];
      r0 = ps.x - xs.x - des_p[n*2];
      r1 = ps.y - xs.y - des_p[n*2 + 1];
      r2 = ps.z - xs.z;
      r3 = ps.w - xs.w;
    } else { r0 = ps.x; r1 = ps.y; r2 = ps.z; r3 = ps.w; }
    sm_relv[gg*4+0] = r0; sm_relv[gg*4+1] = r1; sm_relv[gg*4+2] = r2; sm_relv[gg*4+3] = r3;
    *(float4*)&relg[n*4] = make_float4(r0, r1, r2, r3);
    nwp[n*2]      = des_t[n*2]     - ps.x;
    nwp[n*2 + 1]  = des_t[n*2 + 1] - ps.y;
    nwp2[n*2]     = des_n[n*2]     - ps.x;
    nwp2[n*2 + 1] = des_n[n*2 + 1] - ps.y;
    sm_red[gg] = r0*r0 + r1*r1;
  }
  __syncthreads();
  if (tid == 64) atomicAdd(ss_t, sm_red[0] + sm_red[1] + sm_red[2] + sm_red[3]);

  // ---- P1+P2 fused over ks: hidden (per-ks, VALU) + staged-B MFMA
  float f[8];
  {
    const float4 fa = *(const float4*)&sm_feats[(g*16 + m)*8];
    const float4 fb = *(const float4*)&sm_feats[(g*16 + m)*8 + 4];
    f[0]=fa.x; f[1]=fa.y; f[2]=fa.z; f[3]=fa.w; f[4]=fb.x; f[5]=fb.y; f[6]=fb.z; f[7]=fb.w;
  }
  float4x encR[8];
#pragma unroll
  for (int nt = 0; nt < 8; nt++) encR[nt] = (float4x){0.f,0.f,0.f,0.f};
  const float4* We14 = (const float4*)W_e1;
  const float4* Be14 = (const float4*)b_e1;
  const unsigned short* sb = (const unsigned short*)sm_stage;

  for (int ks = 0; ks < 8; ks++) {
    __syncthreads();
    {
      const uint4* src = (const uint4*)(wsB + (size_t)ks * 8192);
      uint4* dst = (uint4*)sm_stage;
#pragma unroll
      for (int i2 = 0; i2 < 4; i2++) dst[tid + i2*256] = src[tid + i2*256];
    }
    short8x aHi, aLo;
    {
      float h8[8];
      float4 b0 = Be14[8*ks + 2*q];
      float4 b1 = Be14[8*ks + 2*q + 1];
      h8[0]=b0.x; h8[1]=b0.y; h8[2]=b0.z; h8[3]=b0.w; h8[4]=b1.x; h8[5]=b1.y; h8[6]=b1.z; h8[7]=b1.w;
#pragma unroll
      for (int d = 0; d < 8; d++) {
        float4 wa = We14[d*64 + ks*8 + 2*q];
        float4 wb = We14[d*64 + ks*8 + 2*q + 1];
        h8[0] += f[d]*wa.x; h8[1] += f[d]*wa.y; h8[2] += f[d]*wa.z; h8[3] += f[d]*wa.w;
        h8[4] += f[d]*wb.x; h8[5] += f[d]*wb.y; h8[6] += f[d]*wb.z; h8[7] += f[d]*wb.w;
      }
#pragma unroll
      for (int p = 0; p < 8; p++) h8[p] = fmaxf(h8[p], 0.f);
      split8(h8, aHi, aLo);
    }
    __syncthreads();
#pragma unroll
    for (int nt = 0; nt < 8; nt++) {
      short8x bh = *(const short8x*)(sb + nt*1024 + lane*8);
      short8x bl = *(const short8x*)(sb + nt*1024 + 512 + lane*8);
      encR[nt] = __builtin_amdgcn_mfma_f32_16x16x32_bf16(aHi, bl, encR[nt], 0, 0, 0);
      encR[nt] = __builtin_amdgcn_mfma_f32_16x16x32_bf16(aLo, bh, encR[nt], 0, 0, 0);
      encR[nt] = __builtin_amdgcn_mfma_f32_16x16x32_bf16(aHi, bh, encR[nt], 0, 0, 0);
    }
  }
  float4x fl4 = *(const float4x*)&sm_flags[g*16 + q*4];
#pragma unroll
  for (int nt = 0; nt < 8; nt++) {
    float b2 = b_e2[nt*16 + m];
#pragma unroll
    for (int i = 0; i < 4; i++) encR[nt][i] = (encR[nt][i] + b2) * fl4[i];
  }

  // ---- P3: score partials
  float4x part[16];
#pragma unroll
  for (int a = 0; a < 16; a++) part[a] = (float4x){0.f,0.f,0.f,0.f};
#pragma unroll
  for (int a = 0; a < 16; a++) {
#pragma unroll
    for (int nt = 0; nt < 8; nt++) {
      float wv = sm_w1T[a*128 + nt*16 + m];
      part[a] = part[a] + encR[nt] * wv;
    }
  }

  // ---- P4: halving-exchange over m
  const bool s8 = (m & 8) != 0, s4b = (m & 4) != 0, s2b = (m & 2) != 0, s1b = (m & 1) != 0;
  float4x c8[8];
#pragma unroll
  for (int a = 0; a < 8; a++) {
    float4x mi, sd, rc;
#pragma unroll
    for (int e = 0; e < 4; e++) {
      mi[e] = s8 ? part[a+8][e] : part[a][e];
      sd[e] = s8 ? part[a][e] : part[a+8][e];
      rc[e] = __shfl_xor(sd[e], 8);
    }
    c8[a] = mi + rc;
  }
  float4x c4[4];
#pragma unroll
  for (int a = 0; a < 4; a++) {
    float4x mi, sd, rc;
#pragma unroll
    for (int e = 0; e < 4; e++) {
      mi[e] = s4b ? c8[a+4][e] : c8[a][e];
      sd[e] = s4b ? c8[a][e] : c8[a+4][e];
      rc[e] = __shfl_xor(sd[e], 4);
    }
    c4[a] = mi + rc;
  }
  float4x c2[2];
#pragma unroll
  for (int a = 0; a < 2; a++) {
    float4x mi, sd, rc;
#pragma unroll
    for (int e = 0; e < 4; e++) {
      mi[e] = s2b ? c4[a+2][e] : c4[a][e];
      sd[e] = s2b ? c4[a][e] : c4[a+2][e];
      rc[e] = __shfl_xor(sd[e], 2);
    }
    c2[a] = mi + rc;
  }
  float4x c1;
  {
    float4x mi, sd, rc;
#pragma unroll
    for (int e = 0; e < 4; e++) {
      mi[e] = s1b ? c2[1][e] : c2[0][e];
      sd[e] = s1b ? c2[0][e] : c2[1][e];
      rc[e] = __shfl_xor(sd[e], 1);
    }
    c1 = mi + rc;
  }

  // ---- P5: softmax + ctx
  float relw;
  {
    float4 rv = *(const float4*)&sm_relv[g*4];
    relw = rv.x * sm_watt2[m] + rv.y * sm_watt2[16 + m]
         + rv.z * sm_watt2[32 + m] + rv.w * sm_watt2[48 + m];
  }
  float vat = sm_vatt[m];
  float val[4];
#pragma unroll
  for (int i = 0; i < 4; i++) val[i] = tanhf_fast(c1[i] + relw) * vat;
#pragma unroll
  for (int msk = 1; msk < 16; msk <<= 1) {
#pragma unroll
    for (int i = 0; i < 4; i++) val[i] += __shfl_xor(val[i], msk);
  }
  if (q == 3) val[3] = -3.0e38f;
  float mx = fmaxf(fmaxf(val[0], val[1]), fmaxf(val[2], val[3]));
  mx = fmaxf(mx, __shfl_xor(mx, 16));
  mx = fmaxf(mx, __shfl_xor(mx, 32));
  float4x ev;
  float ssum = 0.f;
#pragma unroll
  for (int i = 0; i < 4; i++) { ev[i] = __expf(val[i] - mx); ssum += ev[i]; }
  ssum += __shfl_xor(ssum, 16);
  ssum += __shfl_xor(ssum, 32);
  float inv = 1.f / ssum;
#pragma unroll
  for (int i = 0; i < 4; i++) ev[i] *= inv;

  float cpart[8];
#pragma unroll
  for (int nt = 0; nt < 8; nt++) {
    float cv = ev[0]*encR[nt][0] + ev[1]*encR[nt][1] + ev[2]*encR[nt][2] + ev[3]*encR[nt][3];
    cv += __shfl_xor(cv, 16);
    cv += __shfl_xor(cv, 32);
    cpart[nt] = cv;
  }
  float v0 = (q == 0) ? cpart[0] : (q == 1) ? cpart[2] : (q == 2) ? cpart[4] : cpart[6];
  float v1 = (q == 0) ? cpart[1] : (q == 1) ? cpart[3] : (q == 2) ? cpart[5] : cpart[7];
  size_t cb = (size_t)(n0 + g) * 128 + q*32 + m;
  ctx[cb]      = v0;
  ctx[cb + 16] = v1;
}

// ---------------------------------------------------------------- finalize scalars
__global__ void k_final(const float* __restrict__ ss, float* __restrict__ out) {
  if (threadIdx.x == 0) {
    float t = 0.f;
    for (int i = 0; i < FTS; i++) t += sqrtf(ss[i]);
    out[(size_t)FTS * N_ * 6]     = t / (float)N_;
    out[(size_t)FTS * N_ * 6 + 1] = ss[FTS];
  }
}

// ================================================================ launch
extern "C" void kernel_launch(void* const* d_in, const int* in_sizes, int n_in,
                              void* d_out, int out_size, void* d_ws, size_t ws_size,
                              hipStream_t stream) {
  (void)in_sizes; (void)n_in; (void)out_size;
  const float* x_last    = (const float*)d_in[0];
  const float* x_st_last = (const float*)d_in[1];
  const float* hist_enc  = (const float*)d_in[2];
  const float* z         = (const float*)d_in[3];
  const float* node_size = (const float*)d_in[4];
  const float* W_h0 = (const float*)d_in[5];
  const float* b_h0 = (const float*)d_in[6];
  const float* W_c0 = (const float*)d_in[7];
  const float* b_c0 = (const float*)d_in[8];
  const float* W_gh = (const float*)d_in[9];
  const float* b_gh = (const float*)d_in[10];
  const float* W_gih = (const float*)d_in[11];
  const float* W_ghh = (const float*)d_in[12];
  const float* b_gih = (const float*)d_in[13];
  const float* b_ghh = (const float*)d_in[14];
  const float* W_proj = (const float*)d_in[15];
  const float* b_proj = (const float*)d_in[16];
  const float* W_att1 = (const float*)d_in[17];
  const float* W_att2 = (const float*)d_in[18];
  const float* v_att  = (const float*)d_in[19];
  const float* W_lih = (const float*)d_in[20];
  const float* W_lhh = (const float*)d_in[21];
  const float* b_lih = (const float*)d_in[22];
  const float* b_lhh = (const float*)d_in[23];
  const float* W_e1 = (const float*)d_in[24];
  const float* b_e1 = (const float*)d_in[25];
  const float* W_e2 = (const float*)d_in[26];
  const float* b_e2 = (const float*)d_in[27];
  const float* W_a1 = (const float*)d_in[28];
  const float* b_a1 = (const float*)d_in[29];
  const float* W_a2 = (const float*)d_in[30];
  const float* b_a2 = (const float*)d_in[31];
  const int* e1   = (const int*)d_in[32];
  const int* e2   = (const int*)d_in[33];
  const int* nobs = (const int*)d_in[34];
  float* out = (float*)d_out;

  // workspace carve (floats)
  float* wsf     = (float*)d_ws;
  float* prev    = wsf;
  float* prev_st = wsf + 32768;
  float* des     = wsf + 65536;
  float* ss      = wsf + 262144;
  float* rad     = wsf + 262160;
  float* szf     = wsf + 385040;            // -> end 876560
  float* baseA   = wsf + 876560;            // union region, 5 units of N*256 -> end 11362320
  // serial-phase aliased view
  float* gh0 = baseA;
  float* gh1 = baseA + (size_t)N_ * 256;
  float* gi  = baseA + (size_t)2 * N_ * 256;
  // main phase view
  float* hA   = baseA;
  float* hB   = baseA + (size_t)N_ * 256;
  float* cbuf = baseA + (size_t)2 * N_ * 256;
  float* ctx  = baseA + (size_t)3 * N_ * 256;
  float* rel  = baseA + (size_t)4 * N_ * 256;
  float* nwp  = rel + (size_t)N_ * 4;
  float* nwp2 = nwp + (size_t)N_ * 2;
  // prepped B fragments
  unsigned short* wsBe = (unsigned short*)(wsf + 11362320);
  unsigned short* wsBg = (unsigned short*)(wsf + 11427856);
  unsigned short* wsBl = (unsigned short*)(wsf + 11624464);
  unsigned short* wsBx = (unsigned short*)(wsf + 12017680);
  unsigned short* wsBa = (unsigned short*)(wsf + 12312592);
  float* wattT = wsf + 12386320;                             // -> end 12388368
  // fused-path GRU buffers (disjoint from main-phase aliases): 5 units
  float* ext = wsf + 12388368;
  const size_t needF = 12388368ull + 5ull * N_ * 256ull;     // 22,874,128 floats
  const bool fuse = ws_size >= needF * 4ull;
  float* gh0F = fuse ? ext : gh0;
  float* gh1F = fuse ? (ext + (size_t)N_ * 256) : gh1;
  float* giF  = fuse ? (ext + (size_t)2 * N_ * 256) : gi;

  k_zero<<<1, 64, 0, stream>>>(ss);
  k_edge_static<<<(E_ + 255) / 256, 256, 0, stream>>>(e1, e2, node_size, rad, szf);
  k_init_des<<<FTS * N_ / 256, 256, 0, stream>>>(b_proj, des);
  k_prep_attT<<<8, 256, 0, stream>>>(W_att1, wattT);

  k_prep<<<16,  256, 0, stream>>>(W_e2,  W_e2,  0, 256, 128,  128,  256, 8,  64,  wsBe);
  k_prep<<<96,  256, 0, stream>>>(W_ghh, W_ghh, 0, 256, 768,  768,  256, 48, 384, wsBg);
  k_prep<<<192, 256, 0, stream>>>(W_lih, W_lhh, 0, 128, 1024, 1024, 384, 64, 768, wsBl);
  k_prep<<<144, 256, 0, stream>>>(W_gh,  W_gih, 1, 256, 256,  768,  264, 64, 576, wsBx);
  k_prep<<<36,  256, 0, stream>>>(W_a1,  W_a1,  0, 272, 256,  256,  272, 16, 144, wsBa);

  // guide GRU: prologue steps (2 if fused, all 12 otherwise)
  k_xz_mfma<<<dim3(128, 4), 256, 0, stream>>>(hist_enc, z, wsBx, b_gh, b_gih, gh0F, giF);
  const int pre = fuse ? 2 : FTS;
  float* gcur = gh0F;
  float* gnxt = gh1F;
  for (int t = 0; t < pre; t++) {
    k_gru_mfma<<<dim3(128, 4), 256, 0, stream>>>(gcur, wsBg, b_ghh, giF, W_proj,
                                                 des + (size_t)t * N_ * 2, gnxt);
    float* tmp = gcur; gcur = gnxt; gnxt = tmp;
  }

  // main rollout (gru step t+2 fused into edge dispatch when enabled)
  k_init_hc<<<N_, 256, 0, stream>>>(x_last, x_st_last, W_h0, b_h0, W_c0, b_c0,
                                    hA, cbuf, prev, prev_st);
  float* hcur = hA;
  float* hnxt = hB;
  for (int t = 0; t < FTS; t++) {
    const float* des_t = des + (size_t)t * N_ * 2;
    const float* des_n = des + (size_t)((t + 1 < FTS) ? t + 1 : FTS - 1) * N_ * 2;
    const float* des_p = (t > 0) ? des + (size_t)(t - 1) * N_ * 2 : nullptr;
    const int gs = t + 2;
    const int gru_on = (fuse && gs < FTS) ? 1 : 0;
    const float* gin = (gs & 1) ? gh1F : gh0F;
    float* gout      = (gs & 1) ? gh0F : gh1F;
    float* des_g = des + (size_t)((gs < FTS) ? gs : 0) * N_ * 2;
    k_edge_gru<<<2560, 256, 0, stream>>>(prev, prev_st, x_st_last, szf, rad,
                                         nobs, e1, e2, W_e1, b_e1, wsBe, b_e2,
                                         wattT, W_att2, v_att,
                                         des_p, des_t, des_n,
                                         rel, nwp, nwp2, ctx, ss + t, ss + 12,
                                         gin, wsBg, b_ghh, giF, W_proj, des_g, gout, gru_on);
    k_lstm_mfma<<<dim3(128, 4), 256, 0, stream>>>(ctx, hcur, wsBl, b_lih, b_lhh,
                                                  cbuf, hnxt);
    k_action_mfma<<<256, 256, 0, stream>>>(hnxt, z, rel, nwp, nwp2,
                                           wsBa, b_a1, W_a2, b_a2,
                                           prev, prev_st,
                                           out + (size_t)t * N_ * 4,
                                           out + (size_t)FTS * N_ * 4 + (size_t)t * N_ * 2);
    float* tmp = hcur; hcur = hnxt; hnxt = tmp;
  }
  k_final<<<1, 64, 0, stream>>>(ss, out);
}